// Round 1
// baseline (1269.808 us; speedup 1.0000x reference)
//
#include <hip/hip_runtime.h>
#include <cstdint>
#include <cstddef>

// ---------------- Mamba2 fwd, fp32 baseline ----------------
// B=2 L=2048 Dmodel=1024 Dssm=2048 H=32 P=64 N=128 chunk=256
#define B_SZ   2
#define LQ     2048
#define DMODEL 1024
#define DSSM   2048
#define NH     32
#define HD     64
#define DST    128
#define CONVD  2304
#define DPROJ  4384
#define NC     8
#define CHK    256
#define MROWS  (B_SZ*LQ)   // 4096

__device__ __forceinline__ float silu_f(float x) { return x / (1.f + expf(-x)); }
__device__ __forceinline__ float softplus_f(float x) {
  return fmaxf(x, 0.f) + log1pf(expf(-fabsf(x)));
}

// ============================================================
// Tiled fp32 GEMM, C[m][n] = sum_k A[m][k]*B[n][k]  (both K-major)
// BM=BN=128, BK=16, 256 thr, 8x8 micro-tile, k-major transposed LDS.
// M must be a multiple of 128; N guarded.
// ============================================================
__global__ __launch_bounds__(256, 2) void gemm_nt_kernel(
    const float* __restrict__ A, const float* __restrict__ Bm,
    float* __restrict__ C, int M, int N, int K) {
  __shared__ float As[16][132];
  __shared__ float Bs[16][132];
  const int tid = threadIdx.x;
  const int tx = tid & 15;
  const int ty = tid >> 4;
  const int m0 = blockIdx.y * 128;
  const int n0 = blockIdx.x * 128;
  const int lrow = tid >> 2;      // 0..63
  const int lk = (tid & 3) * 4;   // 0,4,8,12
  float acc[8][8];
#pragma unroll
  for (int i = 0; i < 8; ++i)
#pragma unroll
    for (int j = 0; j < 8; ++j) acc[i][j] = 0.f;

  for (int k0 = 0; k0 < K; k0 += 16) {
#pragma unroll
    for (int hh = 0; hh < 2; ++hh) {
      const int r = lrow + hh * 64;
      float4 av = *(const float4*)&A[(size_t)(m0 + r) * K + k0 + lk];
      As[lk + 0][r] = av.x; As[lk + 1][r] = av.y;
      As[lk + 2][r] = av.z; As[lk + 3][r] = av.w;
      const int gn = n0 + r;
      float4 bv = make_float4(0.f, 0.f, 0.f, 0.f);
      if (gn < N) bv = *(const float4*)&Bm[(size_t)gn * K + k0 + lk];
      Bs[lk + 0][r] = bv.x; Bs[lk + 1][r] = bv.y;
      Bs[lk + 2][r] = bv.z; Bs[lk + 3][r] = bv.w;
    }
    __syncthreads();
#pragma unroll
    for (int k = 0; k < 16; ++k) {
      float a[8], b[8];
      *(float4*)&a[0] = *(const float4*)&As[k][ty * 8];
      *(float4*)&a[4] = *(const float4*)&As[k][ty * 8 + 4];
      *(float4*)&b[0] = *(const float4*)&Bs[k][tx * 8];
      *(float4*)&b[4] = *(const float4*)&Bs[k][tx * 8 + 4];
#pragma unroll
      for (int i = 0; i < 8; ++i)
#pragma unroll
        for (int j = 0; j < 8; ++j)
          acc[i][j] = fmaf(a[i], b[j], acc[i][j]);
    }
    __syncthreads();
  }
#pragma unroll
  for (int i = 0; i < 8; ++i) {
    const int gm = m0 + ty * 8 + i;
#pragma unroll
    for (int j = 0; j < 8; j += 4) {
      const int gn = n0 + tx * 8 + j;
      if (gn < N)
        *(float4*)&C[(size_t)gm * N + gn] =
            make_float4(acc[i][j], acc[i][j + 1], acc[i][j + 2], acc[i][j + 3]);
    }
  }
}

// ============================================================
// Depthwise causal conv(K=4)+bias+SiLU over xBC, plus dt/dA.
// grid = B * (L/16), 256 thr; thread owns channels c = t + 256*j (j<9).
// ============================================================
__global__ __launch_bounds__(256) void conv_dt_kernel(
    const float* __restrict__ zx, const float* __restrict__ conv_w,
    const float* __restrict__ conv_b, const float* __restrict__ dt_bias,
    const float* __restrict__ A_log, float* __restrict__ xconv,
    float* __restrict__ dt_bhl, float* __restrict__ dA_bhl) {
  const int ROWS = 16;
  const int nrb = LQ / ROWS;  // 128
  const int blk = blockIdx.x;
  const int b = blk / nrb;
  const int r0 = (blk % nrb) * ROWS;
  const int t = threadIdx.x;

  float w0[9], w1[9], w2[9], w3[9], bsv[9], h0[9], h1[9], h2[9];
#pragma unroll
  for (int j = 0; j < 9; ++j) {
    const int cch = t + 256 * j;
    w0[j] = conv_w[cch * 4 + 0]; w1[j] = conv_w[cch * 4 + 1];
    w2[j] = conv_w[cch * 4 + 2]; w3[j] = conv_w[cch * 4 + 3];
    bsv[j] = conv_b[cch];
    h0[j] = (r0 - 3 >= 0) ? zx[(size_t)(b * LQ + r0 - 3) * DPROJ + DSSM + cch] : 0.f;
    h1[j] = (r0 - 2 >= 0) ? zx[(size_t)(b * LQ + r0 - 2) * DPROJ + DSSM + cch] : 0.f;
    h2[j] = (r0 - 1 >= 0) ? zx[(size_t)(b * LQ + r0 - 1) * DPROJ + DSSM + cch] : 0.f;
  }
  for (int r = 0; r < ROWS; ++r) {
    const size_t ibase = (size_t)(b * LQ + r0 + r) * DPROJ + DSSM;
    const size_t obase = (size_t)(b * LQ + r0 + r) * CONVD;
#pragma unroll
    for (int j = 0; j < 9; ++j) {
      const int cch = t + 256 * j;
      const float cur = zx[ibase + cch];
      float a = bsv[j] + w0[j] * h0[j] + w1[j] * h1[j] + w2[j] * h2[j] + w3[j] * cur;
      xconv[obase + cch] = silu_f(a);
      h0[j] = h1[j]; h1[j] = h2[j]; h2[j] = cur;
    }
  }
  // dt / dA for these 16 rows (16 rows x 32 heads = 512 = 2 x 256)
#pragma unroll
  for (int j = 0; j < 2; ++j) {
    const int idx = t + 256 * j;
    const int r = idx >> 5;
    const int hh = idx & 31;
    const int row = r0 + r;
    float raw = zx[(size_t)(b * LQ + row) * DPROJ + (DSSM + CONVD) + hh] + dt_bias[hh];
    float dtv = softplus_f(raw);
    const size_t o = ((size_t)b * NH + hh) * LQ + row;
    dt_bhl[o] = dtv;
    dA_bhl[o] = -expf(A_log[hh]) * dtv;
  }
}

// ============================================================
// Per (b,c,h): block scan of dA over chunk, then
// states[p][n] = sum_l B[l,n] * exp(T - cs[l]) * dt[l] * x[l,p]
// ============================================================
__global__ __launch_bounds__(256) void chunk_states_kernel(
    const float* __restrict__ xconv, const float* __restrict__ dt_bhl,
    const float* __restrict__ dA_bhl, float* __restrict__ dA_cs_g,
    float* __restrict__ Tg, float* __restrict__ states) {
  const int blk = blockIdx.x;
  const int h = blk & (NH - 1);
  const int c = (blk / NH) & (NC - 1);
  const int b = blk / (NH * NC);
  const int t = threadIdx.x;
  __shared__ float cs[CHK];
  __shared__ float Bsh[64][132];
  __shared__ float Xsh[64][68];
  const size_t bh = (size_t)b * NH + h;
  const int rowbase = b * LQ + c * CHK;

  cs[t] = dA_bhl[bh * LQ + c * CHK + t];
  __syncthreads();
#pragma unroll
  for (int off = 1; off < CHK; off <<= 1) {
    const float add = (t >= off) ? cs[t - off] : 0.f;
    __syncthreads();
    cs[t] += add;
    __syncthreads();
  }
  const float total = cs[CHK - 1];
  dA_cs_g[(bh * NC + c) * CHK + t] = cs[t];
  if (t == 0) Tg[bh * NC + c] = total;

  float acc[4][8];
#pragma unroll
  for (int i = 0; i < 4; ++i)
#pragma unroll
    for (int j = 0; j < 8; ++j) acc[i][j] = 0.f;
  const int pq = (t >> 4) * 4;  // p base
  const int nb = (t & 15) * 8;  // n base

  for (int lt = 0; lt < 4; ++lt) {
    const int l0 = lt * 64;
    {
      const int r = t >> 5;
      const int nq = (t & 31) * 4;
#pragma unroll
      for (int j = 0; j < 8; ++j) {
        const int rr = r + j * 8;
        float4 bv = *(const float4*)&xconv[(size_t)(rowbase + l0 + rr) * CONVD + DSSM + nq];
        *(float4*)&Bsh[rr][nq] = bv;
      }
      const int r2 = t >> 4;
      const int pq2 = (t & 15) * 4;
#pragma unroll
      for (int j = 0; j < 4; ++j) {
        const int rr = r2 + j * 16;
        const float f = dt_bhl[bh * LQ + c * CHK + l0 + rr] * expf(total - cs[l0 + rr]);
        float4 xv = *(const float4*)&xconv[(size_t)(rowbase + l0 + rr) * CONVD + h * HD + pq2];
        xv.x *= f; xv.y *= f; xv.z *= f; xv.w *= f;
        *(float4*)&Xsh[rr][pq2] = xv;
      }
    }
    __syncthreads();
#pragma unroll 4
    for (int l = 0; l < 64; ++l) {
      float4 x4 = *(const float4*)&Xsh[l][pq];
      float4 b4a = *(const float4*)&Bsh[l][nb];
      float4 b4b = *(const float4*)&Bsh[l][nb + 4];
      const float xv[4] = {x4.x, x4.y, x4.z, x4.w};
      const float bv[8] = {b4a.x, b4a.y, b4a.z, b4a.w, b4b.x, b4b.y, b4b.z, b4b.w};
#pragma unroll
      for (int i = 0; i < 4; ++i)
#pragma unroll
        for (int j = 0; j < 8; ++j)
          acc[i][j] = fmaf(xv[i], bv[j], acc[i][j]);
    }
    __syncthreads();
  }
  const size_t sbase = ((size_t)((b * NC + c) * NH) + h) * (HD * DST);
#pragma unroll
  for (int i = 0; i < 4; ++i) {
    *(float4*)&states[sbase + (size_t)(pq + i) * DST + nb] =
        make_float4(acc[i][0], acc[i][1], acc[i][2], acc[i][3]);
    *(float4*)&states[sbase + (size_t)(pq + i) * DST + nb + 4] =
        make_float4(acc[i][4], acc[i][5], acc[i][6], acc[i][7]);
  }
}

// ============================================================
// Inter-chunk recurrence, IN-PLACE: states[c] <- P_c (prev state),
// P_{c+1} = exp(T_c)*P_c + states_c.  grid = B*H*8 slices, 4 elem/thr.
// ============================================================
__global__ __launch_bounds__(256) void chunk_scan_kernel(
    float* __restrict__ states, const float* __restrict__ Tg) {
  const int blk = blockIdx.x;
  const int s = blk & 7;
  const int bh = blk >> 3;
  const int b = bh / NH;
  const int h = bh % NH;
  const int e = s * 1024 + threadIdx.x * 4;
  float4 P = make_float4(0.f, 0.f, 0.f, 0.f);
#pragma unroll
  for (int c = 0; c < NC; ++c) {
    const size_t idx = ((size_t)((b * NC + c) * NH) + h) * (HD * DST) + e;
    float4 S = *(float4*)&states[idx];
    *(float4*)&states[idx] = P;
    const float ec = expf(Tg[(size_t)bh * NC + c]);
    P.x = fmaf(ec, P.x, S.x); P.y = fmaf(ec, P.y, S.y);
    P.z = fmaf(ec, P.z, S.z); P.w = fmaf(ec, P.w, S.w);
  }
}

// ============================================================
// Per (b,c,h): Y = (L ∘ C B^T) X  +  exp(cs)⊙(C prev^T)  +  D*x
// flash-style 64x64 tiles, only lower-triangular tile pairs.
// ============================================================
__global__ __launch_bounds__(256) void y_kernel(
    const float* __restrict__ xconv, const float* __restrict__ dt_bhl,
    const float* __restrict__ dA_cs_g, const float* __restrict__ prev,
    const float* __restrict__ Dp, float* __restrict__ y) {
  const int blk = blockIdx.x;
  const int h = blk & (NH - 1);
  const int c = (blk / NH) & (NC - 1);
  const int b = blk / (NH * NC);
  const int t = threadIdx.x;
  const int tl = t >> 4;  // 0..15 (l-frag)
  const int tq = t & 15;  // 0..15 (s/p-frag)
  __shared__ float cs[CHK];
  __shared__ float CtT[DST][68];
  __shared__ float BtT[DST][68];  // also holds prev^T
  __shared__ float Xt[64][68];
  __shared__ float GsT[64][68];
  const size_t bh = (size_t)b * NH + h;
  cs[t] = dA_cs_g[(bh * NC + c) * CHK + t];
  const float Dh = Dp[h];
  const size_t prevbase = ((size_t)((b * NC + c) * NH) + h) * (HD * DST);
  const int rowbase = b * LQ + c * CHK;
  __syncthreads();

  for (int lt = 0; lt < 4; ++lt) {
    const int l0 = lt * 64;
    {  // stage C-tile^T and prev^T
      const int r = t >> 5;
      const int nq = (t & 31) * 4;
#pragma unroll
      for (int j = 0; j < 8; ++j) {
        const int rr = r + j * 8;
        float4 cv = *(const float4*)&xconv[(size_t)(rowbase + l0 + rr) * CONVD + (DSSM + DST) + nq];
        CtT[nq + 0][rr] = cv.x; CtT[nq + 1][rr] = cv.y;
        CtT[nq + 2][rr] = cv.z; CtT[nq + 3][rr] = cv.w;
        float4 pv = *(const float4*)&prev[prevbase + (size_t)rr * DST + nq];
        BtT[nq + 0][rr] = pv.x; BtT[nq + 1][rr] = pv.y;
        BtT[nq + 2][rr] = pv.z; BtT[nq + 3][rr] = pv.w;
      }
    }
    __syncthreads();
    float Y[4][4] = {{0.f}};
    // Y_off = C @ prev^T
#pragma unroll 8
    for (int n = 0; n < DST; ++n) {
      float4 a4 = *(const float4*)&CtT[n][tl * 4];
      float4 p4 = *(const float4*)&BtT[n][tq * 4];
      const float av[4] = {a4.x, a4.y, a4.z, a4.w};
      const float pv[4] = {p4.x, p4.y, p4.z, p4.w};
#pragma unroll
      for (int i = 0; i < 4; ++i)
#pragma unroll
        for (int j = 0; j < 4; ++j)
          Y[i][j] = fmaf(av[i], pv[j], Y[i][j]);
    }
#pragma unroll
    for (int i = 0; i < 4; ++i) {
      const float e = expf(cs[l0 + tl * 4 + i]);
#pragma unroll
      for (int j = 0; j < 4; ++j) Y[i][j] *= e;
    }
    __syncthreads();  // done reading prev^T from BtT

    for (int st = 0; st <= lt; ++st) {
      const int s0 = st * 64;
      {  // stage B-tile^T and X-tile (x*dt)
        const int r = t >> 5;
        const int nq = (t & 31) * 4;
#pragma unroll
        for (int j = 0; j < 8; ++j) {
          const int rr = r + j * 8;
          float4 bv = *(const float4*)&xconv[(size_t)(rowbase + s0 + rr) * CONVD + DSSM + nq];
          BtT[nq + 0][rr] = bv.x; BtT[nq + 1][rr] = bv.y;
          BtT[nq + 2][rr] = bv.z; BtT[nq + 3][rr] = bv.w;
        }
        const int r2 = t >> 4;
        const int pq = (t & 15) * 4;
#pragma unroll
        for (int j = 0; j < 4; ++j) {
          const int ss2 = r2 + j * 16;
          const float f = dt_bhl[bh * LQ + c * CHK + s0 + ss2];
          float4 xv = *(const float4*)&xconv[(size_t)(rowbase + s0 + ss2) * CONVD + h * HD + pq];
          xv.x *= f; xv.y *= f; xv.z *= f; xv.w *= f;
          *(float4*)&Xt[ss2][pq] = xv;
        }
      }
      __syncthreads();
      float G[4][4] = {{0.f}};
#pragma unroll 8
      for (int n = 0; n < DST; ++n) {
        float4 a4 = *(const float4*)&CtT[n][tl * 4];
        float4 b4 = *(const float4*)&BtT[n][tq * 4];
        const float av[4] = {a4.x, a4.y, a4.z, a4.w};
        const float bv[4] = {b4.x, b4.y, b4.z, b4.w};
#pragma unroll
        for (int i = 0; i < 4; ++i)
#pragma unroll
          for (int j = 0; j < 4; ++j)
            G[i][j] = fmaf(av[i], bv[j], G[i][j]);
      }
      // decay + causal mask, scatter G^T to LDS
#pragma unroll
      for (int i = 0; i < 4; ++i) {
        const int ll = l0 + tl * 4 + i;
        const float cl = cs[ll];
#pragma unroll
        for (int j = 0; j < 4; ++j) {
          const int ss = s0 + tq * 4 + j;
          const float g = (ll >= ss) ? G[i][j] * expf(cl - cs[ss]) : 0.f;
          GsT[tq * 4 + j][tl * 4 + i] = g;
        }
      }
      __syncthreads();
#pragma unroll 8
      for (int s = 0; s < 64; ++s) {
        float4 g4 = *(const float4*)&GsT[s][tl * 4];
        float4 x4 = *(const float4*)&Xt[s][tq * 4];
        const float gv[4] = {g4.x, g4.y, g4.z, g4.w};
        const float xv[4] = {x4.x, x4.y, x4.z, x4.w};
#pragma unroll
        for (int i = 0; i < 4; ++i)
#pragma unroll
          for (int j = 0; j < 4; ++j)
            Y[i][j] = fmaf(gv[i], xv[j], Y[i][j]);
      }
      __syncthreads();
    }
    // epilogue: + D*x, store y
#pragma unroll
    for (int i = 0; i < 4; ++i) {
      const int grow = rowbase + l0 + tl * 4 + i;
      float4 xv = *(const float4*)&xconv[(size_t)grow * CONVD + h * HD + tq * 4];
      float4 o;
      o.x = Y[i][0] + Dh * xv.x;
      o.y = Y[i][1] + Dh * xv.y;
      o.z = Y[i][2] + Dh * xv.z;
      o.w = Y[i][3] + Dh * xv.w;
      *(float4*)&y[(size_t)grow * DSSM + h * HD + tq * 4] = o;
    }
    __syncthreads();
  }
}

// ============================================================
// yg = y*silu(z); yg *= rsqrt(mean(yg^2)+eps)*norm_w  (in-place on y)
// ============================================================
__global__ __launch_bounds__(256) void gate_norm_kernel(
    const float* __restrict__ zx, const float* __restrict__ norm_w,
    float* __restrict__ y) {
  const int m = blockIdx.x;
  const int t = threadIdx.x;
  __shared__ float red[4];
  float g[8];
  float ssum = 0.f;
#pragma unroll
  for (int j = 0; j < 2; ++j) {
    const int cb = t * 4 + j * 1024;
    float4 yv = *(const float4*)&y[(size_t)m * DSSM + cb];
    float4 zv = *(const float4*)&zx[(size_t)m * DPROJ + cb];
    const float yy[4] = {yv.x, yv.y, yv.z, yv.w};
    const float zz[4] = {zv.x, zv.y, zv.z, zv.w};
#pragma unroll
    for (int q = 0; q < 4; ++q) {
      const float gv = yy[q] * silu_f(zz[q]);
      g[j * 4 + q] = gv;
      ssum = fmaf(gv, gv, ssum);
    }
  }
#pragma unroll
  for (int off = 32; off > 0; off >>= 1) ssum += __shfl_down(ssum, off, 64);
  if ((t & 63) == 0) red[t >> 6] = ssum;
  __syncthreads();
  const float tot = red[0] + red[1] + red[2] + red[3];
  const float sc = 1.0f / sqrtf(tot / (float)DSSM + 1e-5f);
#pragma unroll
  for (int j = 0; j < 2; ++j) {
    const int cb = t * 4 + j * 1024;
    float4 nw = *(const float4*)&norm_w[cb];
    float4 o;
    o.x = g[j * 4 + 0] * sc * nw.x;
    o.y = g[j * 4 + 1] * sc * nw.y;
    o.z = g[j * 4 + 2] * sc * nw.z;
    o.w = g[j * 4 + 3] * sc * nw.w;
    *(float4*)&y[(size_t)m * DSSM + cb] = o;
  }
}

// ============================================================
extern "C" void kernel_launch(void* const* d_in, const int* in_sizes, int n_in,
                              void* d_out, int out_size, void* d_ws, size_t ws_size,
                              hipStream_t stream) {
  const float* u          = (const float*)d_in[0];
  const float* in_proj_w  = (const float*)d_in[1];
  const float* conv_w     = (const float*)d_in[2];
  const float* conv_b     = (const float*)d_in[3];
  const float* dt_bias    = (const float*)d_in[4];
  const float* A_log      = (const float*)d_in[5];
  const float* Dp         = (const float*)d_in[6];
  const float* norm_w     = (const float*)d_in[7];
  const float* out_proj_w = (const float*)d_in[8];
  float* out = (float*)d_out;

  float* ws = (float*)d_ws;
  float* zx     = ws;                                   // 4096*4384
  float* xconv  = zx     + (size_t)MROWS * DPROJ;       // 4096*2304
  float* dt_bhl = xconv  + (size_t)MROWS * CONVD;       // B*H*L
  float* dA_bhl = dt_bhl + (size_t)B_SZ * NH * LQ;
  float* dA_cs  = dA_bhl + (size_t)B_SZ * NH * LQ;
  float* Tg     = dA_cs  + (size_t)B_SZ * NH * LQ;
  float* states = Tg     + (size_t)B_SZ * NH * NC;      // B*NC*H*64*128
  float* ybuf   = states + (size_t)B_SZ * NC * NH * HD * DST;  // 4096*2048
  // total ~161.5 MB of d_ws

  // 1) zxbcdt = u @ in_proj_w^T
  gemm_nt_kernel<<<dim3((DPROJ + 127) / 128, MROWS / 128), 256, 0, stream>>>(
      u, in_proj_w, zx, MROWS, DPROJ, DMODEL);
  // 2) causal dwconv + SiLU, dt/dA
  conv_dt_kernel<<<dim3(B_SZ * (LQ / 16)), 256, 0, stream>>>(
      zx, conv_w, conv_b, dt_bias, A_log, xconv, dt_bhl, dA_bhl);
  // 3) per-chunk cumsum + intra-chunk states
  chunk_states_kernel<<<dim3(B_SZ * NC * NH), 256, 0, stream>>>(
      xconv, dt_bhl, dA_bhl, dA_cs, Tg, states);
  // 4) inter-chunk recurrence (in-place: states -> prev_states)
  chunk_scan_kernel<<<dim3(B_SZ * NH * 8), 256, 0, stream>>>(states, Tg);
  // 5) Y = diag + off + D*x
  y_kernel<<<dim3(B_SZ * NC * NH), 256, 0, stream>>>(
      xconv, dt_bhl, dA_cs, states, Dp, ybuf);
  // 6) gate + RMSNorm (in-place on ybuf)
  gate_norm_kernel<<<dim3(MROWS), 256, 0, stream>>>(zx, norm_w, ybuf);
  // 7) out = yg @ out_proj_w^T
  gemm_nt_kernel<<<dim3(DMODEL / 128, MROWS / 128), 256, 0, stream>>>(
      ybuf, out_proj_w, out, MROWS, DMODEL, DSSM);
}

// Round 2
// 758.573 us; speedup vs baseline: 1.6739x; 1.6739x over previous
//
#include <hip/hip_runtime.h>
#include <cstdint>
#include <cstddef>

// ---------------- Mamba2 fwd: bf16-MFMA projections + fp32 SSM core ----------------
// B=2 L=2048 Dmodel=1024 Dssm=2048 H=32 P=64 N=128 chunk=256
#define B_SZ   2
#define LQ     2048
#define DMODEL 1024
#define DSSM   2048
#define NH     32
#define HD     64
#define DST    128
#define CONVD  2304
#define DPROJ  4384
#define NC     8
#define CHK    256
#define MROWS  (B_SZ*LQ)   // 4096

__device__ __forceinline__ float silu_f(float x) { return x / (1.f + expf(-x)); }
__device__ __forceinline__ float softplus_f(float x) {
  return fmaxf(x, 0.f) + log1pf(expf(-fabsf(x)));
}
__device__ __forceinline__ ushort f2bf(float f) {  // RNE fp32->bf16
  uint32_t u = __float_as_uint(f);
  uint32_t r = (u + 0x7FFFu + ((u >> 16) & 1u)) >> 16;
  return (ushort)r;
}

typedef __bf16 bf16x8 __attribute__((ext_vector_type(8)));
typedef float f32x4 __attribute__((ext_vector_type(4)));

// ============================================================
// cast fp32 -> bf16 (as ushort), 4 elems/thread
// ============================================================
__global__ __launch_bounds__(256) void cast_f32_bf16_kernel(
    const float* __restrict__ in, ushort* __restrict__ out, int n) {
  const int i = (blockIdx.x * 256 + threadIdx.x) * 4;
  if (i >= n) return;
  float4 v = *(const float4*)&in[i];
  ushort4 o;
  o.x = f2bf(v.x); o.y = f2bf(v.y); o.z = f2bf(v.z); o.w = f2bf(v.w);
  *(ushort4*)&out[i] = o;
}

// ============================================================
// bf16 MFMA GEMM (NT): C[m][n] = sum_k A[m][k]*B[n][k], fp32 out.
// 128x128 tile, BK=64, 4 waves (2x2 of 64x64), 16x16x32 MFMA.
// Reg-staged LDS with T2 XOR swizzle (elem ^= ((row&7)<<3)).
// M,K multiples of 128/64; N guarded.
// ============================================================
__global__ __launch_bounds__(256, 2) void gemm_nt_bf16(
    const ushort* __restrict__ A, const ushort* __restrict__ Bm,
    float* __restrict__ C, int M, int N, int K) {
  __shared__ ushort As[128 * 64];
  __shared__ ushort Bs[128 * 64];
  const int t = threadIdx.x;
  const int lane = t & 63;
  const int wid = t >> 6;
  const int wm = (wid >> 1) * 64;
  const int wn = (wid & 1) * 64;
  const int lr = lane & 15;
  const int lk = (lane >> 4) * 8;
  const int m0 = blockIdx.y * 128;
  const int n0 = blockIdx.x * 128;
  const int srow = t >> 3;        // 0..31
  const int sce = (t & 7) * 8;    // 0..56, elem offset (16B granules)

  f32x4 acc[4][4];
#pragma unroll
  for (int i = 0; i < 4; ++i)
#pragma unroll
    for (int j = 0; j < 4; ++j) acc[i][j] = (f32x4){0.f, 0.f, 0.f, 0.f};

  const int NT = K >> 6;
  for (int kt = 0; kt < NT; ++kt) {
    const int k0 = kt << 6;
    uint4 ar[4], br[4];
#pragma unroll
    for (int s2 = 0; s2 < 4; ++s2) {
      const int row = srow + s2 * 32;
      ar[s2] = *(const uint4*)&A[(size_t)(m0 + row) * K + k0 + sce];
      const int gn = n0 + row;
      br[s2] = (gn < N) ? *(const uint4*)&Bm[(size_t)gn * K + k0 + sce]
                        : make_uint4(0u, 0u, 0u, 0u);
    }
    __syncthreads();   // previous compute finished reading LDS
#pragma unroll
    for (int s2 = 0; s2 < 4; ++s2) {
      const int row = srow + s2 * 32;
      const int e = (row * 64 + sce) ^ ((row & 7) << 3);
      *(uint4*)&As[e] = ar[s2];
      *(uint4*)&Bs[e] = br[s2];
    }
    __syncthreads();
#pragma unroll
    for (int ks = 0; ks < 2; ++ks) {
      bf16x8 af[4], bfr[4];
#pragma unroll
      for (int i = 0; i < 4; ++i) {
        const int ra = wm + i * 16 + lr;
        const int ea = (ra * 64 + ks * 32 + lk) ^ ((ra & 7) << 3);
        af[i] = *(const bf16x8*)&As[ea];
        const int rb = wn + i * 16 + lr;
        const int eb = (rb * 64 + ks * 32 + lk) ^ ((rb & 7) << 3);
        bfr[i] = *(const bf16x8*)&Bs[eb];
      }
#pragma unroll
      for (int i = 0; i < 4; ++i)
#pragma unroll
        for (int j = 0; j < 4; ++j)
          acc[i][j] = __builtin_amdgcn_mfma_f32_16x16x32_bf16(af[i], bfr[j], acc[i][j], 0, 0, 0);
    }
  }
  // epilogue: D col = lane&15, row = (lane>>4)*4 + q  (m89-verified layout)
  const int r4 = (lane >> 4) * 4;
#pragma unroll
  for (int i = 0; i < 4; ++i) {
#pragma unroll
    for (int j = 0; j < 4; ++j) {
      const int col = n0 + wn + j * 16 + lr;
      if (col < N) {
#pragma unroll
        for (int q = 0; q < 4; ++q) {
          const int row = m0 + wm + i * 16 + r4 + q;
          C[(size_t)row * N + col] = acc[i][j][q];
        }
      }
    }
  }
}

// ============================================================
// fp32 dt: dt_raw[m][h] = u[m,:] . W[4352+h,:]  (fixes bf16 GEMM's
// dt columns -- these feed exp(cumsum) amplification).
// One row per block; 8 threads per head.
// ============================================================
__global__ __launch_bounds__(256) void dt_kernel(
    const float* __restrict__ u, const float* __restrict__ w,
    const float* __restrict__ dt_bias, const float* __restrict__ A_log,
    float* __restrict__ dt_bhl, float* __restrict__ dA_bhl) {
  const int m = blockIdx.x;  // 0..4095
  const int b = m >> 11;
  const int l = m & 2047;
  __shared__ float us[DMODEL];
  const int t = threadIdx.x;
  *(float4*)&us[t * 4] = *(const float4*)&u[(size_t)m * DMODEL + t * 4];
  __syncthreads();
  const int h = t >> 3;
  const int seg = t & 7;
  const float* wr = &w[(size_t)(DSSM + CONVD + h) * DMODEL + seg * 128];
  const float* uu = &us[seg * 128];
  float s = 0.f;
#pragma unroll
  for (int k = 0; k < 128; k += 4) {
    float4 wv = *(const float4*)&wr[k];
    s = fmaf(wv.x, uu[k + 0], s);
    s = fmaf(wv.y, uu[k + 1], s);
    s = fmaf(wv.z, uu[k + 2], s);
    s = fmaf(wv.w, uu[k + 3], s);
  }
  s += __shfl_down(s, 4, 8);
  s += __shfl_down(s, 2, 8);
  s += __shfl_down(s, 1, 8);
  if (seg == 0) {
    const float dtv = softplus_f(s + dt_bias[h]);
    const size_t o = ((size_t)b * NH + h) * LQ + l;
    dt_bhl[o] = dtv;
    dA_bhl[o] = -expf(A_log[h]) * dtv;
  }
}

// ============================================================
// Depthwise causal conv(K=4)+bias+SiLU over xBC.
// ============================================================
__global__ __launch_bounds__(256) void conv_kernel(
    const float* __restrict__ zx, const float* __restrict__ conv_w,
    const float* __restrict__ conv_b, float* __restrict__ xconv) {
  const int ROWS = 16;
  const int nrb = LQ / ROWS;  // 128
  const int blk = blockIdx.x;
  const int b = blk / nrb;
  const int r0 = (blk % nrb) * ROWS;
  const int t = threadIdx.x;

  float w0[9], w1[9], w2[9], w3[9], bsv[9], h0[9], h1[9], h2[9];
#pragma unroll
  for (int j = 0; j < 9; ++j) {
    const int cch = t + 256 * j;
    w0[j] = conv_w[cch * 4 + 0]; w1[j] = conv_w[cch * 4 + 1];
    w2[j] = conv_w[cch * 4 + 2]; w3[j] = conv_w[cch * 4 + 3];
    bsv[j] = conv_b[cch];
    h0[j] = (r0 - 3 >= 0) ? zx[(size_t)(b * LQ + r0 - 3) * DPROJ + DSSM + cch] : 0.f;
    h1[j] = (r0 - 2 >= 0) ? zx[(size_t)(b * LQ + r0 - 2) * DPROJ + DSSM + cch] : 0.f;
    h2[j] = (r0 - 1 >= 0) ? zx[(size_t)(b * LQ + r0 - 1) * DPROJ + DSSM + cch] : 0.f;
  }
  for (int r = 0; r < ROWS; ++r) {
    const size_t ibase = (size_t)(b * LQ + r0 + r) * DPROJ + DSSM;
    const size_t obase = (size_t)(b * LQ + r0 + r) * CONVD;
#pragma unroll
    for (int j = 0; j < 9; ++j) {
      const int cch = t + 256 * j;
      const float cur = zx[ibase + cch];
      float a = bsv[j] + w0[j] * h0[j] + w1[j] * h1[j] + w2[j] * h2[j] + w3[j] * cur;
      xconv[obase + cch] = silu_f(a);
      h0[j] = h1[j]; h1[j] = h2[j]; h2[j] = cur;
    }
  }
}

// ============================================================
// Per (b,c,h): block scan of dA over chunk, then
// states[p][n] = sum_l B[l,n] * exp(T - cs[l]) * dt[l] * x[l,p]
// ============================================================
__global__ __launch_bounds__(256) void chunk_states_kernel(
    const float* __restrict__ xconv, const float* __restrict__ dt_bhl,
    const float* __restrict__ dA_bhl, float* __restrict__ dA_cs_g,
    float* __restrict__ Tg, float* __restrict__ states) {
  const int blk = blockIdx.x;
  const int h = blk & (NH - 1);
  const int c = (blk / NH) & (NC - 1);
  const int b = blk / (NH * NC);
  const int t = threadIdx.x;
  __shared__ float cs[CHK];
  __shared__ float Bsh[64][132];
  __shared__ float Xsh[64][68];
  const size_t bh = (size_t)b * NH + h;
  const int rowbase = b * LQ + c * CHK;

  cs[t] = dA_bhl[bh * LQ + c * CHK + t];
  __syncthreads();
#pragma unroll
  for (int off = 1; off < CHK; off <<= 1) {
    const float add = (t >= off) ? cs[t - off] : 0.f;
    __syncthreads();
    cs[t] += add;
    __syncthreads();
  }
  const float total = cs[CHK - 1];
  dA_cs_g[(bh * NC + c) * CHK + t] = cs[t];
  if (t == 0) Tg[bh * NC + c] = total;

  float acc[4][8];
#pragma unroll
  for (int i = 0; i < 4; ++i)
#pragma unroll
    for (int j = 0; j < 8; ++j) acc[i][j] = 0.f;
  const int pq = (t >> 4) * 4;  // p base
  const int nb = (t & 15) * 8;  // n base

  for (int lt = 0; lt < 4; ++lt) {
    const int l0 = lt * 64;
    {
      const int r = t >> 5;
      const int nq = (t & 31) * 4;
#pragma unroll
      for (int j = 0; j < 8; ++j) {
        const int rr = r + j * 8;
        float4 bv = *(const float4*)&xconv[(size_t)(rowbase + l0 + rr) * CONVD + DSSM + nq];
        *(float4*)&Bsh[rr][nq] = bv;
      }
      const int r2 = t >> 4;
      const int pq2 = (t & 15) * 4;
#pragma unroll
      for (int j = 0; j < 4; ++j) {
        const int rr = r2 + j * 16;
        const float f = dt_bhl[bh * LQ + c * CHK + l0 + rr] * expf(total - cs[l0 + rr]);
        float4 xv = *(const float4*)&xconv[(size_t)(rowbase + l0 + rr) * CONVD + h * HD + pq2];
        xv.x *= f; xv.y *= f; xv.z *= f; xv.w *= f;
        *(float4*)&Xsh[rr][pq2] = xv;
      }
    }
    __syncthreads();
#pragma unroll 4
    for (int l = 0; l < 64; ++l) {
      float4 x4 = *(const float4*)&Xsh[l][pq];
      float4 b4a = *(const float4*)&Bsh[l][nb];
      float4 b4b = *(const float4*)&Bsh[l][nb + 4];
      const float xv[4] = {x4.x, x4.y, x4.z, x4.w};
      const float bv[8] = {b4a.x, b4a.y, b4a.z, b4a.w, b4b.x, b4b.y, b4b.z, b4b.w};
#pragma unroll
      for (int i = 0; i < 4; ++i)
#pragma unroll
        for (int j = 0; j < 8; ++j)
          acc[i][j] = fmaf(xv[i], bv[j], acc[i][j]);
    }
    __syncthreads();
  }
  const size_t sbase = ((size_t)((b * NC + c) * NH) + h) * (HD * DST);
#pragma unroll
  for (int i = 0; i < 4; ++i) {
    *(float4*)&states[sbase + (size_t)(pq + i) * DST + nb] =
        make_float4(acc[i][0], acc[i][1], acc[i][2], acc[i][3]);
    *(float4*)&states[sbase + (size_t)(pq + i) * DST + nb + 4] =
        make_float4(acc[i][4], acc[i][5], acc[i][6], acc[i][7]);
  }
}

// ============================================================
// Inter-chunk recurrence, IN-PLACE: states[c] <- P_c (prev state)
// ============================================================
__global__ __launch_bounds__(256) void chunk_scan_kernel(
    float* __restrict__ states, const float* __restrict__ Tg) {
  const int blk = blockIdx.x;
  const int s = blk & 7;
  const int bh = blk >> 3;
  const int b = bh / NH;
  const int h = bh % NH;
  const int e = s * 1024 + threadIdx.x * 4;
  float4 P = make_float4(0.f, 0.f, 0.f, 0.f);
#pragma unroll
  for (int c = 0; c < NC; ++c) {
    const size_t idx = ((size_t)((b * NC + c) * NH) + h) * (HD * DST) + e;
    float4 S = *(float4*)&states[idx];
    *(float4*)&states[idx] = P;
    const float ec = expf(Tg[(size_t)bh * NC + c]);
    P.x = fmaf(ec, P.x, S.x); P.y = fmaf(ec, P.y, S.y);
    P.z = fmaf(ec, P.z, S.z); P.w = fmaf(ec, P.w, S.w);
  }
}

// ============================================================
// Per (b,c,h): Y = (L ∘ C B^T) X  +  exp(cs)⊙(C prev^T)  +  D*x
// ============================================================
__global__ __launch_bounds__(256) void y_kernel(
    const float* __restrict__ xconv, const float* __restrict__ dt_bhl,
    const float* __restrict__ dA_cs_g, const float* __restrict__ prev,
    const float* __restrict__ Dp, float* __restrict__ y) {
  const int blk = blockIdx.x;
  const int h = blk & (NH - 1);
  const int c = (blk / NH) & (NC - 1);
  const int b = blk / (NH * NC);
  const int t = threadIdx.x;
  const int tl = t >> 4;  // 0..15 (l-frag)
  const int tq = t & 15;  // 0..15 (s/p-frag)
  __shared__ float cs[CHK];
  __shared__ float CtT[DST][68];
  __shared__ float BtT[DST][68];  // also holds prev^T
  __shared__ float Xt[64][68];
  __shared__ float GsT[64][68];
  const size_t bh = (size_t)b * NH + h;
  cs[t] = dA_cs_g[(bh * NC + c) * CHK + t];
  const float Dh = Dp[h];
  const size_t prevbase = ((size_t)((b * NC + c) * NH) + h) * (HD * DST);
  const int rowbase = b * LQ + c * CHK;
  __syncthreads();

  for (int lt = 0; lt < 4; ++lt) {
    const int l0 = lt * 64;
    {  // stage C-tile^T and prev^T
      const int r = t >> 5;
      const int nq = (t & 31) * 4;
#pragma unroll
      for (int j = 0; j < 8; ++j) {
        const int rr = r + j * 8;
        float4 cv = *(const float4*)&xconv[(size_t)(rowbase + l0 + rr) * CONVD + (DSSM + DST) + nq];
        CtT[nq + 0][rr] = cv.x; CtT[nq + 1][rr] = cv.y;
        CtT[nq + 2][rr] = cv.z; CtT[nq + 3][rr] = cv.w;
        float4 pv = *(const float4*)&prev[prevbase + (size_t)rr * DST + nq];
        BtT[nq + 0][rr] = pv.x; BtT[nq + 1][rr] = pv.y;
        BtT[nq + 2][rr] = pv.z; BtT[nq + 3][rr] = pv.w;
      }
    }
    __syncthreads();
    float Y[4][4] = {{0.f}};
#pragma unroll 8
    for (int n = 0; n < DST; ++n) {
      float4 a4 = *(const float4*)&CtT[n][tl * 4];
      float4 p4 = *(const float4*)&BtT[n][tq * 4];
      const float av[4] = {a4.x, a4.y, a4.z, a4.w};
      const float pv[4] = {p4.x, p4.y, p4.z, p4.w};
#pragma unroll
      for (int i = 0; i < 4; ++i)
#pragma unroll
        for (int j = 0; j < 4; ++j)
          Y[i][j] = fmaf(av[i], pv[j], Y[i][j]);
    }
#pragma unroll
    for (int i = 0; i < 4; ++i) {
      const float e = expf(cs[l0 + tl * 4 + i]);
#pragma unroll
      for (int j = 0; j < 4; ++j) Y[i][j] *= e;
    }
    __syncthreads();  // done reading prev^T from BtT

    for (int st = 0; st <= lt; ++st) {
      const int s0 = st * 64;
      {  // stage B-tile^T and X-tile (x*dt)
        const int r = t >> 5;
        const int nq = (t & 31) * 4;
#pragma unroll
        for (int j = 0; j < 8; ++j) {
          const int rr = r + j * 8;
          float4 bv = *(const float4*)&xconv[(size_t)(rowbase + s0 + rr) * CONVD + DSSM + nq];
          BtT[nq + 0][rr] = bv.x; BtT[nq + 1][rr] = bv.y;
          BtT[nq + 2][rr] = bv.z; BtT[nq + 3][rr] = bv.w;
        }
        const int r2 = t >> 4;
        const int pq = (t & 15) * 4;
#pragma unroll
        for (int j = 0; j < 4; ++j) {
          const int ss2 = r2 + j * 16;
          const float f = dt_bhl[bh * LQ + c * CHK + s0 + ss2];
          float4 xv = *(const float4*)&xconv[(size_t)(rowbase + s0 + ss2) * CONVD + h * HD + pq];
          xv.x *= f; xv.y *= f; xv.z *= f; xv.w *= f;
          *(float4*)&Xt[ss2][pq] = xv;
        }
      }
      __syncthreads();
      float G[4][4] = {{0.f}};
#pragma unroll 8
      for (int n = 0; n < DST; ++n) {
        float4 a4 = *(const float4*)&CtT[n][tl * 4];
        float4 b4 = *(const float4*)&BtT[n][tq * 4];
        const float av[4] = {a4.x, a4.y, a4.z, a4.w};
        const float bv[4] = {b4.x, b4.y, b4.z, b4.w};
#pragma unroll
        for (int i = 0; i < 4; ++i)
#pragma unroll
          for (int j = 0; j < 4; ++j)
            G[i][j] = fmaf(av[i], bv[j], G[i][j]);
      }
#pragma unroll
      for (int i = 0; i < 4; ++i) {
        const int ll = l0 + tl * 4 + i;
        const float cl = cs[ll];
#pragma unroll
        for (int j = 0; j < 4; ++j) {
          const int ss = s0 + tq * 4 + j;
          const float g = (ll >= ss) ? G[i][j] * expf(cl - cs[ss]) : 0.f;
          GsT[tq * 4 + j][tl * 4 + i] = g;
        }
      }
      __syncthreads();
#pragma unroll 8
      for (int s = 0; s < 64; ++s) {
        float4 g4 = *(const float4*)&GsT[s][tl * 4];
        float4 x4 = *(const float4*)&Xt[s][tq * 4];
        const float gv[4] = {g4.x, g4.y, g4.z, g4.w};
        const float xv[4] = {x4.x, x4.y, x4.z, x4.w};
#pragma unroll
        for (int i = 0; i < 4; ++i)
#pragma unroll
          for (int j = 0; j < 4; ++j)
            Y[i][j] = fmaf(gv[i], xv[j], Y[i][j]);
      }
      __syncthreads();
    }
#pragma unroll
    for (int i = 0; i < 4; ++i) {
      const int grow = rowbase + l0 + tl * 4 + i;
      float4 xv = *(const float4*)&xconv[(size_t)grow * CONVD + h * HD + tq * 4];
      float4 o;
      o.x = Y[i][0] + Dh * xv.x;
      o.y = Y[i][1] + Dh * xv.y;
      o.z = Y[i][2] + Dh * xv.z;
      o.w = Y[i][3] + Dh * xv.w;
      *(float4*)&y[(size_t)grow * DSSM + h * HD + tq * 4] = o;
    }
    __syncthreads();
  }
}

// ============================================================
// yg = y*silu(z); yg *= rsqrt(mean(yg^2)+eps)*norm_w  (in-place on y)
// ============================================================
__global__ __launch_bounds__(256) void gate_norm_kernel(
    const float* __restrict__ zx, const float* __restrict__ norm_w,
    float* __restrict__ y) {
  const int m = blockIdx.x;
  const int t = threadIdx.x;
  __shared__ float red[4];
  float g[8];
  float ssum = 0.f;
#pragma unroll
  for (int j = 0; j < 2; ++j) {
    const int cb = t * 4 + j * 1024;
    float4 yv = *(const float4*)&y[(size_t)m * DSSM + cb];
    float4 zv = *(const float4*)&zx[(size_t)m * DPROJ + cb];
    const float yy[4] = {yv.x, yv.y, yv.z, yv.w};
    const float zz[4] = {zv.x, zv.y, zv.z, zv.w};
#pragma unroll
    for (int q = 0; q < 4; ++q) {
      const float gv = yy[q] * silu_f(zz[q]);
      g[j * 4 + q] = gv;
      ssum = fmaf(gv, gv, ssum);
    }
  }
#pragma unroll
  for (int off = 32; off > 0; off >>= 1) ssum += __shfl_down(ssum, off, 64);
  if ((t & 63) == 0) red[t >> 6] = ssum;
  __syncthreads();
  const float tot = red[0] + red[1] + red[2] + red[3];
  const float sc = 1.0f / sqrtf(tot / (float)DSSM + 1e-5f);
#pragma unroll
  for (int j = 0; j < 2; ++j) {
    const int cb = t * 4 + j * 1024;
    float4 nw = *(const float4*)&norm_w[cb];
    float4 o;
    o.x = g[j * 4 + 0] * sc * nw.x;
    o.y = g[j * 4 + 1] * sc * nw.y;
    o.z = g[j * 4 + 2] * sc * nw.z;
    o.w = g[j * 4 + 3] * sc * nw.w;
    *(float4*)&y[(size_t)m * DSSM + cb] = o;
  }
}

// ============================================================
extern "C" void kernel_launch(void* const* d_in, const int* in_sizes, int n_in,
                              void* d_out, int out_size, void* d_ws, size_t ws_size,
                              hipStream_t stream) {
  const float* u          = (const float*)d_in[0];
  const float* in_proj_w  = (const float*)d_in[1];
  const float* conv_w     = (const float*)d_in[2];
  const float* conv_b     = (const float*)d_in[3];
  const float* dt_bias    = (const float*)d_in[4];
  const float* A_log      = (const float*)d_in[5];
  const float* Dp         = (const float*)d_in[6];
  const float* norm_w     = (const float*)d_in[7];
  const float* out_proj_w = (const float*)d_in[8];
  float* out = (float*)d_out;

  float* ws = (float*)d_ws;
  float* zx     = ws;                                   // 4096*4384 f
  float* xconv  = zx     + (size_t)MROWS * DPROJ;       // 4096*2304 f
  float* dt_bhl = xconv  + (size_t)MROWS * CONVD;
  float* dA_bhl = dt_bhl + (size_t)B_SZ * NH * LQ;
  float* dA_cs  = dA_bhl + (size_t)B_SZ * NH * LQ;
  float* Tg     = dA_cs  + (size_t)B_SZ * NH * LQ;
  float* states = Tg     + (size_t)B_SZ * NH * NC;      // 2*8*32*64*128 f
  float* ybuf   = states + (size_t)B_SZ * NC * NH * HD * DST;  // 4096*2048 f
  // bf16 buffers alias dead fp32 regions (footprint unchanged ~161.5 MB):
  ushort* u_bf  = (ushort*)ybuf;                        // dead before y_kernel writes ybuf
  ushort* w_bf  = u_bf + (size_t)MROWS * DMODEL;
  ushort* y_bf  = (ushort*)states;                      // states dead after y_kernel
  ushort* ow_bf = (ushort*)xconv;                       // xconv dead after y_kernel

  const int n_u = MROWS * DMODEL;       // 4194304
  const int n_w = DPROJ * DMODEL;       // 4489216
  const int n_y = MROWS * DSSM;         // 8388608
  const int n_o = DMODEL * DSSM;        // 2097152

  // 1) casts for in_proj
  cast_f32_bf16_kernel<<<dim3(n_u / 1024), 256, 0, stream>>>(u, u_bf, n_u);
  cast_f32_bf16_kernel<<<dim3(n_w / 1024), 256, 0, stream>>>(in_proj_w, w_bf, n_w);
  // 2) zxbcdt = u @ in_proj_w^T  (bf16 MFMA, fp32 out)
  gemm_nt_bf16<<<dim3((DPROJ + 127) / 128, MROWS / 128), 256, 0, stream>>>(
      u_bf, w_bf, zx, MROWS, DPROJ, DMODEL);
  // 3) fp32 dt / dA (accuracy-critical path recomputed in fp32)
  dt_kernel<<<dim3(MROWS), 256, 0, stream>>>(u, in_proj_w, dt_bias, A_log, dt_bhl, dA_bhl);
  // 4) causal dwconv + SiLU
  conv_kernel<<<dim3(B_SZ * (LQ / 16)), 256, 0, stream>>>(zx, conv_w, conv_b, xconv);
  // 5) per-chunk cumsum + intra-chunk states
  chunk_states_kernel<<<dim3(B_SZ * NC * NH), 256, 0, stream>>>(
      xconv, dt_bhl, dA_bhl, dA_cs, Tg, states);
  // 6) inter-chunk recurrence
  chunk_scan_kernel<<<dim3(B_SZ * NH * 8), 256, 0, stream>>>(states, Tg);
  // 7) Y = diag + off + D*x
  y_kernel<<<dim3(B_SZ * NC * NH), 256, 0, stream>>>(
      xconv, dt_bhl, dA_cs, states, Dp, ybuf);
  // 8) cast out_proj_w (xconv now dead)
  cast_f32_bf16_kernel<<<dim3(n_o / 1024), 256, 0, stream>>>(out_proj_w, ow_bf, n_o);
  // 9) gate + RMSNorm (in-place on ybuf)
  gate_norm_kernel<<<dim3(MROWS), 256, 0, stream>>>(zx, norm_w, ybuf);
  // 10) cast yg -> bf16 (states now dead)
  cast_f32_bf16_kernel<<<dim3(n_y / 1024), 256, 0, stream>>>(ybuf, y_bf, n_y);
  // 11) out = yg @ out_proj_w^T  (bf16 MFMA, fp32 out)
  gemm_nt_bf16<<<dim3(DMODEL / 128, MROWS / 128), 256, 0, stream>>>(
      y_bf, ow_bf, out, MROWS, DMODEL, DSSM);
}

// Round 4
// 530.507 us; speedup vs baseline: 2.3936x; 1.4299x over previous
//
#include <hip/hip_runtime.h>
#include <cstdint>
#include <cstddef>

// ---------------- Mamba2 fwd: bf16-MFMA projections + bf16-MFMA SSM core ----------------
// B=2 L=2048 Dmodel=1024 Dssm=2048 H=32 P=64 N=128 chunk=256
#define B_SZ   2
#define LQ     2048
#define DMODEL 1024
#define DSSM   2048
#define NH     32
#define HD     64
#define DST    128
#define CONVD  2304
#define DPROJ  4384
#define NC     8
#define CHK    256
#define MROWS  (B_SZ*LQ)   // 4096

// XOR swizzles: SWZ256 for 256B-pitch LDS rows (conflict-free frag reads),
// SWZ64 for 128B-pitch rows (2-way max).
#define SWZ256(r) (((r) & 15) << 4)
#define SWZ64(r)  (((((r) & 7) ^ (((r) >> 3) & 7))) << 4)

__device__ __forceinline__ float silu_f(float x) { return x / (1.f + expf(-x)); }
__device__ __forceinline__ float softplus_f(float x) {
  return fmaxf(x, 0.f) + log1pf(expf(-fabsf(x)));
}
__device__ __forceinline__ ushort f2bf(float f) {  // RNE fp32->bf16
  uint32_t u = __float_as_uint(f);
  uint32_t r = (u + 0x7FFFu + ((u >> 16) & 1u)) >> 16;
  return (ushort)r;
}
__device__ __forceinline__ float bf2f(ushort u) {
  return __uint_as_float(((uint32_t)u) << 16);
}
__device__ __forceinline__ uint32_t pk2(float a, float b) {
  return (uint32_t)f2bf(a) | ((uint32_t)f2bf(b) << 16);
}

typedef __bf16 bf16x8 __attribute__((ext_vector_type(8)));
typedef float f32x4 __attribute__((ext_vector_type(4)));

// ============================================================
// cast fp32 -> bf16 (as ushort), 4 elems/thread
// ============================================================
__global__ __launch_bounds__(256) void cast_f32_bf16_kernel(
    const float* __restrict__ in, ushort* __restrict__ out, int n) {
  const int i = (blockIdx.x * 256 + threadIdx.x) * 4;
  if (i >= n) return;
  float4 v = *(const float4*)&in[i];
  ushort4 o;
  o.x = f2bf(v.x); o.y = f2bf(v.y); o.z = f2bf(v.z); o.w = f2bf(v.w);
  *(ushort4*)&out[i] = o;
}

// ============================================================
// bf16 MFMA GEMM (NT): C[m][n] = sum_k A[m][k]*B[n][k], fp32 out.
// 128x128 tile, BK=64, 4 waves (2x2 of 64x64), 16x16x32 MFMA.
// ============================================================
__global__ __launch_bounds__(256, 2) void gemm_nt_bf16(
    const ushort* __restrict__ A, const ushort* __restrict__ Bm,
    float* __restrict__ C, int M, int N, int K) {
  __shared__ ushort As[128 * 64];
  __shared__ ushort Bs[128 * 64];
  const int t = threadIdx.x;
  const int lane = t & 63;
  const int wid = t >> 6;
  const int wm = (wid >> 1) * 64;
  const int wn = (wid & 1) * 64;
  const int lr = lane & 15;
  const int lk = (lane >> 4) * 8;
  const int m0 = blockIdx.y * 128;
  const int n0 = blockIdx.x * 128;
  const int srow = t >> 3;
  const int sce = (t & 7) * 8;

  f32x4 acc[4][4];
#pragma unroll
  for (int i = 0; i < 4; ++i)
#pragma unroll
    for (int j = 0; j < 4; ++j) acc[i][j] = (f32x4){0.f, 0.f, 0.f, 0.f};

  const int NT = K >> 6;
  for (int kt = 0; kt < NT; ++kt) {
    const int k0 = kt << 6;
    uint4 ar[4], br[4];
#pragma unroll
    for (int s2 = 0; s2 < 4; ++s2) {
      const int row = srow + s2 * 32;
      ar[s2] = *(const uint4*)&A[(size_t)(m0 + row) * K + k0 + sce];
      const int gn = n0 + row;
      br[s2] = (gn < N) ? *(const uint4*)&Bm[(size_t)gn * K + k0 + sce]
                        : make_uint4(0u, 0u, 0u, 0u);
    }
    __syncthreads();
#pragma unroll
    for (int s2 = 0; s2 < 4; ++s2) {
      const int row = srow + s2 * 32;
      const int e = (row * 64 + sce) ^ ((row & 7) << 3);
      *(uint4*)&As[e] = ar[s2];
      *(uint4*)&Bs[e] = br[s2];
    }
    __syncthreads();
#pragma unroll
    for (int ks = 0; ks < 2; ++ks) {
      bf16x8 af[4], bfr[4];
#pragma unroll
      for (int i = 0; i < 4; ++i) {
        const int ra = wm + i * 16 + lr;
        const int ea = (ra * 64 + ks * 32 + lk) ^ ((ra & 7) << 3);
        af[i] = *(const bf16x8*)&As[ea];
        const int rb = wn + i * 16 + lr;
        const int eb = (rb * 64 + ks * 32 + lk) ^ ((rb & 7) << 3);
        bfr[i] = *(const bf16x8*)&Bs[eb];
      }
#pragma unroll
      for (int i = 0; i < 4; ++i)
#pragma unroll
        for (int j = 0; j < 4; ++j)
          acc[i][j] = __builtin_amdgcn_mfma_f32_16x16x32_bf16(af[i], bfr[j], acc[i][j], 0, 0, 0);
    }
  }
  const int r4 = (lane >> 4) * 4;
#pragma unroll
  for (int i = 0; i < 4; ++i) {
#pragma unroll
    for (int j = 0; j < 4; ++j) {
      const int col = n0 + wn + j * 16 + lr;
      if (col < N) {
#pragma unroll
        for (int q = 0; q < 4; ++q) {
          const int row = m0 + wm + i * 16 + r4 + q;
          C[(size_t)row * N + col] = acc[i][j][q];
        }
      }
    }
  }
}

// ============================================================
// fp32 dt: recompute dt columns exactly (exp-amplified path)
// ============================================================
__global__ __launch_bounds__(256) void dt_kernel(
    const float* __restrict__ u, const float* __restrict__ w,
    const float* __restrict__ dt_bias, const float* __restrict__ A_log,
    float* __restrict__ dt_bhl, float* __restrict__ dA_bhl) {
  const int m = blockIdx.x;
  const int b = m >> 11;
  const int l = m & 2047;
  __shared__ float us[DMODEL];
  const int t = threadIdx.x;
  *(float4*)&us[t * 4] = *(const float4*)&u[(size_t)m * DMODEL + t * 4];
  __syncthreads();
  const int h = t >> 3;
  const int seg = t & 7;
  const float* wr = &w[(size_t)(DSSM + CONVD + h) * DMODEL + seg * 128];
  const float* uu = &us[seg * 128];
  float s = 0.f;
#pragma unroll
  for (int k = 0; k < 128; k += 4) {
    float4 wv = *(const float4*)&wr[k];
    s = fmaf(wv.x, uu[k + 0], s);
    s = fmaf(wv.y, uu[k + 1], s);
    s = fmaf(wv.z, uu[k + 2], s);
    s = fmaf(wv.w, uu[k + 3], s);
  }
  s += __shfl_down(s, 4, 8);
  s += __shfl_down(s, 2, 8);
  s += __shfl_down(s, 1, 8);
  if (seg == 0) {
    const float dtv = softplus_f(s + dt_bias[h]);
    const size_t o = ((size_t)b * NH + h) * LQ + l;
    dt_bhl[o] = dtv;
    dA_bhl[o] = -expf(A_log[h]) * dtv;
  }
}

// ============================================================
// Depthwise causal conv(K=4)+bias+SiLU over xBC (fp32 out).
// ============================================================
__global__ __launch_bounds__(256) void conv_kernel(
    const float* __restrict__ zx, const float* __restrict__ conv_w,
    const float* __restrict__ conv_b, float* __restrict__ xconv) {
  const int ROWS = 16;
  const int nrb = LQ / ROWS;
  const int blk = blockIdx.x;
  const int b = blk / nrb;
  const int r0 = (blk % nrb) * ROWS;
  const int t = threadIdx.x;

  float w0[9], w1[9], w2[9], w3[9], bsv[9], h0[9], h1[9], h2[9];
#pragma unroll
  for (int j = 0; j < 9; ++j) {
    const int cch = t + 256 * j;
    w0[j] = conv_w[cch * 4 + 0]; w1[j] = conv_w[cch * 4 + 1];
    w2[j] = conv_w[cch * 4 + 2]; w3[j] = conv_w[cch * 4 + 3];
    bsv[j] = conv_b[cch];
    h0[j] = (r0 - 3 >= 0) ? zx[(size_t)(b * LQ + r0 - 3) * DPROJ + DSSM + cch] : 0.f;
    h1[j] = (r0 - 2 >= 0) ? zx[(size_t)(b * LQ + r0 - 2) * DPROJ + DSSM + cch] : 0.f;
    h2[j] = (r0 - 1 >= 0) ? zx[(size_t)(b * LQ + r0 - 1) * DPROJ + DSSM + cch] : 0.f;
  }
  for (int r = 0; r < ROWS; ++r) {
    const size_t ibase = (size_t)(b * LQ + r0 + r) * DPROJ + DSSM;
    const size_t obase = (size_t)(b * LQ + r0 + r) * CONVD;
#pragma unroll
    for (int j = 0; j < 9; ++j) {
      const int cch = t + 256 * j;
      const float cur = zx[ibase + cch];
      float a = bsv[j] + w0[j] * h0[j] + w1[j] * h1[j] + w2[j] * h2[j] + w3[j] * cur;
      xconv[obase + cch] = silu_f(a);
      h0[j] = h1[j]; h1[j] = h2[j]; h2[j] = cur;
    }
  }
}

// ============================================================
// Stage a [64 rows][128 cols] fp32 tile -> bf16 LDS, 256B pitch,
// SWZ256 swizzle. 256 thr: 4/row, 32 f32 each (coalesced 128B).
// ============================================================
__device__ __forceinline__ void stage_tile_128w(
    ushort* sh, const float* __restrict__ src, int src_stride, int t) {
  const int r = t >> 2;
  const int cb = (t & 3) * 32;
  const float* s = &src[(size_t)r * src_stride + cb];
  float4 v0 = *(const float4*)&s[0],  v1 = *(const float4*)&s[4];
  float4 v2 = *(const float4*)&s[8],  v3 = *(const float4*)&s[12];
  float4 v4 = *(const float4*)&s[16], v5 = *(const float4*)&s[20];
  float4 v6 = *(const float4*)&s[24], v7 = *(const float4*)&s[28];
  uint4 q0 = make_uint4(pk2(v0.x, v0.y), pk2(v0.z, v0.w), pk2(v1.x, v1.y), pk2(v1.z, v1.w));
  uint4 q1 = make_uint4(pk2(v2.x, v2.y), pk2(v2.z, v2.w), pk2(v3.x, v3.y), pk2(v3.z, v3.w));
  uint4 q2 = make_uint4(pk2(v4.x, v4.y), pk2(v4.z, v4.w), pk2(v5.x, v5.y), pk2(v5.z, v5.w));
  uint4 q3 = make_uint4(pk2(v6.x, v6.y), pk2(v6.z, v6.w), pk2(v7.x, v7.y), pk2(v7.z, v7.w));
  char* shb = (char*)sh + r * 256;
  const int c0 = cb * 2;
  *(uint4*)(shb + ((c0 +  0) ^ SWZ256(r))) = q0;
  *(uint4*)(shb + ((c0 + 16) ^ SWZ256(r))) = q1;
  *(uint4*)(shb + ((c0 + 32) ^ SWZ256(r))) = q2;
  *(uint4*)(shb + ((c0 + 48) ^ SWZ256(r))) = q3;
}

// ============================================================
// Per (b,c,h): cumsum(dA) scan + intra-chunk states via MFMA:
// states[p][n] = sum_l Xd[p][l] * Bd[n][l],  Xd = x*dt*exp(total-cs)
// 4 waves split n (128) into 4x32. Output bf16.
// ============================================================
__global__ __launch_bounds__(256) void chunk_states_mfma(
    const float* __restrict__ xconv, const float* __restrict__ dt_bhl,
    const float* __restrict__ dA_bhl, float* __restrict__ dA_cs_g,
    float* __restrict__ Tg, ushort* __restrict__ states_bf) {
  const int blk = blockIdx.x;
  const int h = blk & (NH - 1);
  const int c = (blk / NH) & (NC - 1);
  const int b = blk / (NH * NC);
  const int t = threadIdx.x;
  const int lane = t & 63;
  const int wid = t >> 6;
  const int lr = lane & 15;
  const int lk = lane >> 4;
  __shared__ float cs[CHK];
  __shared__ ushort Xt2[64 * 64];   // [p][l] 128B pitch, SWZ64
  __shared__ ushort Bt2[128 * 64];  // [n][l] 128B pitch, SWZ64
  const size_t bh = (size_t)b * NH + h;
  const int rowbase = b * LQ + c * CHK;

  cs[t] = dA_bhl[bh * LQ + c * CHK + t];
  __syncthreads();
#pragma unroll
  for (int off = 1; off < CHK; off <<= 1) {
    const float add = (t >= off) ? cs[t - off] : 0.f;
    __syncthreads();
    cs[t] += add;
    __syncthreads();
  }
  const float total = cs[CHK - 1];
  dA_cs_g[(bh * NC + c) * CHK + t] = cs[t];
  if (t == 0) Tg[bh * NC + c] = total;

  f32x4 acc[4][2];
#pragma unroll
  for (int i = 0; i < 4; ++i)
#pragma unroll
    for (int j = 0; j < 2; ++j) acc[i][j] = (f32x4){0.f, 0.f, 0.f, 0.f};

  for (int lt = 0; lt < 4; ++lt) {
    const int l0 = lt * 64;
    __syncthreads();
    {  // stage Xt2: rows l -> [p][l], factor dt*exp(total-cs)
      const int sr = t >> 2;
      const int pb = (t & 3) * 16;
      const float f = dt_bhl[bh * LQ + c * CHK + l0 + sr] * expf(total - cs[l0 + sr]);
      const float* xs = &xconv[(size_t)(rowbase + l0 + sr) * CONVD + h * HD + pb];
      float xv[16];
      *(float4*)&xv[0] = *(const float4*)&xs[0];
      *(float4*)&xv[4] = *(const float4*)&xs[4];
      *(float4*)&xv[8] = *(const float4*)&xs[8];
      *(float4*)&xv[12] = *(const float4*)&xs[12];
      char* Xb = (char*)Xt2;
#pragma unroll
      for (int e = 0; e < 16; ++e) {
        const int p = pb + e;
        *(ushort*)(Xb + (p * 128 + ((sr * 2) ^ SWZ64(p)))) = f2bf(xv[e] * f);
      }
    }
    {  // stage Bt2: rows l -> [n][l]
      const int sr = t >> 2;
      const int nb = (t & 3) * 32;
      const float* bs = &xconv[(size_t)(rowbase + l0 + sr) * CONVD + DSSM + nb];
      float bv[32];
#pragma unroll
      for (int q = 0; q < 8; ++q) *(float4*)&bv[q * 4] = *(const float4*)&bs[q * 4];
      char* Bb = (char*)Bt2;
#pragma unroll
      for (int e = 0; e < 32; ++e) {
        const int n = nb + e;
        *(ushort*)(Bb + (n * 128 + ((sr * 2) ^ SWZ64(n)))) = f2bf(bv[e]);
      }
    }
    __syncthreads();
#pragma unroll
    for (int ks = 0; ks < 2; ++ks) {
      const int kb = (ks * 32 + lk * 8) * 2;
      bf16x8 a4[4], b2[2];
#pragma unroll
      for (int i = 0; i < 4; ++i) {
        const int p = i * 16 + lr;
        a4[i] = *(const bf16x8*)((char*)Xt2 + (p * 128 + (kb ^ SWZ64(p))));
      }
#pragma unroll
      for (int j = 0; j < 2; ++j) {
        const int n = wid * 32 + j * 16 + lr;
        b2[j] = *(const bf16x8*)((char*)Bt2 + (n * 128 + (kb ^ SWZ64(n))));
      }
#pragma unroll
      for (int i = 0; i < 4; ++i)
#pragma unroll
        for (int j = 0; j < 2; ++j)
          acc[i][j] = __builtin_amdgcn_mfma_f32_16x16x32_bf16(a4[i], b2[j], acc[i][j], 0, 0, 0);
    }
  }
  const size_t sbase = ((size_t)((b * NC + c) * NH) + h) * (HD * DST);
#pragma unroll
  for (int i = 0; i < 4; ++i)
#pragma unroll
    for (int j = 0; j < 2; ++j)
#pragma unroll
      for (int q = 0; q < 4; ++q) {
        const int p = i * 16 + lk * 4 + q;
        const int n = wid * 32 + j * 16 + lr;
        states_bf[sbase + (size_t)p * DST + n] = f2bf(acc[i][j][q]);
      }
}

// ============================================================
// Inter-chunk recurrence: reads states_bf, keeps P fp32, writes prev_bf.
// ============================================================
__global__ __launch_bounds__(256) void chunk_scan_kernel(
    const ushort* __restrict__ states_bf, ushort* __restrict__ prev_bf,
    const float* __restrict__ Tg) {
  const int blk = blockIdx.x;
  const int s = blk & 7;
  const int bh = blk >> 3;
  const int b = bh / NH;
  const int h = bh % NH;
  const int e = s * 1024 + threadIdx.x * 4;
  float4 P = make_float4(0.f, 0.f, 0.f, 0.f);
#pragma unroll
  for (int c = 0; c < NC; ++c) {
    const size_t idx = ((size_t)((b * NC + c) * NH) + h) * (HD * DST) + e;
    ushort4 s4 = *(const ushort4*)&states_bf[idx];
    ushort4 o;
    o.x = f2bf(P.x); o.y = f2bf(P.y); o.z = f2bf(P.z); o.w = f2bf(P.w);
    *(ushort4*)&prev_bf[idx] = o;
    const float ec = expf(Tg[(size_t)bh * NC + c]);
    P.x = fmaf(ec, P.x, bf2f(s4.x)); P.y = fmaf(ec, P.y, bf2f(s4.y));
    P.z = fmaf(ec, P.z, bf2f(s4.z)); P.w = fmaf(ec, P.w, bf2f(s4.w));
  }
}

// ============================================================
// Per (b,c,h): Y = (L ∘ C B^T) X + exp(cs)⊙(C prev^T) + D*x  via MFMA.
// 4 waves as 2x2 over the 64(l)x64(p) output tile; lt outer loop.
// Output y in bf16.
// ============================================================
__global__ __launch_bounds__(256) void y_mfma_kernel(
    const float* __restrict__ xconv, const float* __restrict__ dt_bhl,
    const float* __restrict__ dA_cs_g, const ushort* __restrict__ prevb,
    const float* __restrict__ Dp, ushort* __restrict__ ybf) {
  const int blk = blockIdx.x;
  const int h = blk & (NH - 1);
  const int c = (blk / NH) & (NC - 1);
  const int b = blk / (NH * NC);
  const int t = threadIdx.x;
  const int lane = t & 63;
  const int wid = t >> 6;
  const int wr = (wid >> 1) * 32;   // l-range base of this wave
  const int wc = (wid & 1) * 32;    // p/s-range base of this wave
  const int lr = lane & 15;
  const int lk = lane >> 4;
  __shared__ float cs[CHK];
  __shared__ ushort Ct[64 * 128];   // C tile, 256B pitch, SWZ256
  __shared__ ushort Bs[64 * 128];   // B tile, 256B pitch, SWZ256
  __shared__ ushort Gt[64 * 64];    // G tile (l x s), 128B pitch, SWZ64
  __shared__ ushort Xt[64 * 64];    // X^T tile (p x s), 128B pitch, SWZ64
  const size_t bh = (size_t)b * NH + h;
  const size_t prevbase = ((size_t)((b * NC + c) * NH) + h) * (HD * DST);
  const int rowbase = b * LQ + c * CHK;
  cs[t] = dA_cs_g[(bh * NC + c) * CHK + t];
  const float Dh = Dp[h];
  __syncthreads();

  for (int lt = 0; lt < 4; ++lt) {
    const int l0 = lt * 64;
    __syncthreads();  // protect Ct/Gt/Xt from previous iteration readers
    stage_tile_128w(Ct, &xconv[(size_t)(rowbase + l0) * CONVD + DSSM + DST], CONVD, t);
    __syncthreads();
    // cache A-fragments of C (reused by off-term and all G tiles)
    bf16x8 af[2][4];
#pragma unroll
    for (int i = 0; i < 2; ++i)
#pragma unroll
      for (int ks = 0; ks < 4; ++ks) {
        const int row = wr + i * 16 + lr;
        af[i][ks] = *(const bf16x8*)((char*)Ct +
            (row * 256 + (((ks * 32 + lk * 8) * 2) ^ SWZ256(row))));
      }
    // off-term: C @ prev^T (B-frags direct from global), then * exp(cs[l])
    f32x4 acc[2][2];
#pragma unroll
    for (int i = 0; i < 2; ++i)
#pragma unroll
      for (int j = 0; j < 2; ++j) acc[i][j] = (f32x4){0.f, 0.f, 0.f, 0.f};
#pragma unroll
    for (int ks = 0; ks < 4; ++ks) {
      bf16x8 bp[2];
#pragma unroll
      for (int j = 0; j < 2; ++j) {
        const int p = wc + j * 16 + lr;
        bp[j] = *(const bf16x8*)&prevb[prevbase + (size_t)p * DST + ks * 32 + lk * 8];
      }
#pragma unroll
      for (int i = 0; i < 2; ++i)
#pragma unroll
        for (int j = 0; j < 2; ++j)
          acc[i][j] = __builtin_amdgcn_mfma_f32_16x16x32_bf16(af[i][ks], bp[j], acc[i][j], 0, 0, 0);
    }
#pragma unroll
    for (int i = 0; i < 2; ++i) {
#pragma unroll
      for (int q = 0; q < 4; ++q) {
        const float e = expf(cs[l0 + wr + i * 16 + lk * 4 + q]);
        acc[i][0][q] *= e;
        acc[i][1][q] *= e;
      }
    }

    for (int st = 0; st <= lt; ++st) {
      const int s0 = st * 64;
      __syncthreads();  // prior Bs/Xt/Gt readers done
      stage_tile_128w(Bs, &xconv[(size_t)(rowbase + s0) * CONVD + DSSM], CONVD, t);
      {  // stage Xt: rows s of x*dt -> [p][s]
        const int sr = t >> 2;
        const int pb = (t & 3) * 16;
        const float f = dt_bhl[bh * LQ + c * CHK + s0 + sr];
        const float* xs = &xconv[(size_t)(rowbase + s0 + sr) * CONVD + h * HD + pb];
        float xv[16];
        *(float4*)&xv[0] = *(const float4*)&xs[0];
        *(float4*)&xv[4] = *(const float4*)&xs[4];
        *(float4*)&xv[8] = *(const float4*)&xs[8];
        *(float4*)&xv[12] = *(const float4*)&xs[12];
        char* Xb = (char*)Xt;
#pragma unroll
        for (int e = 0; e < 16; ++e) {
          const int p = pb + e;
          *(ushort*)(Xb + (p * 128 + ((sr * 2) ^ SWZ64(p)))) = f2bf(xv[e] * f);
        }
      }
      __syncthreads();
      // G = C B^T
      f32x4 g2[2][2];
#pragma unroll
      for (int i = 0; i < 2; ++i)
#pragma unroll
        for (int j = 0; j < 2; ++j) g2[i][j] = (f32x4){0.f, 0.f, 0.f, 0.f};
#pragma unroll
      for (int ks = 0; ks < 4; ++ks) {
        bf16x8 bb[2];
#pragma unroll
        for (int j = 0; j < 2; ++j) {
          const int srow = wc + j * 16 + lr;
          bb[j] = *(const bf16x8*)((char*)Bs +
              (srow * 256 + (((ks * 32 + lk * 8) * 2) ^ SWZ256(srow))));
        }
#pragma unroll
        for (int i = 0; i < 2; ++i)
#pragma unroll
          for (int j = 0; j < 2; ++j)
            g2[i][j] = __builtin_amdgcn_mfma_f32_16x16x32_bf16(af[i][ks], bb[j], g2[i][j], 0, 0, 0);
      }
      // decay + causal mask, write G^(bf16) to LDS
      {
        char* Gb = (char*)Gt;
#pragma unroll
        for (int i = 0; i < 2; ++i) {
#pragma unroll
          for (int q = 0; q < 4; ++q) {
            const int lloc = wr + i * 16 + lk * 4 + q;
            const int labs = l0 + lloc;
            const float cl = cs[labs];
#pragma unroll
            for (int j = 0; j < 2; ++j) {
              const int sloc = wc + j * 16 + lr;
              const int sabs = s0 + sloc;
              const float gv = (labs >= sabs) ? g2[i][j][q] * expf(cl - cs[sabs]) : 0.f;
              *(ushort*)(Gb + (lloc * 128 + ((sloc * 2) ^ SWZ64(lloc)))) = f2bf(gv);
            }
          }
        }
      }
      __syncthreads();
      // Y += G X
#pragma unroll
      for (int ks2 = 0; ks2 < 2; ++ks2) {
        const int kb = (ks2 * 32 + lk * 8) * 2;
        bf16x8 ga[2], xb[2];
#pragma unroll
        for (int i = 0; i < 2; ++i) {
          const int lloc = wr + i * 16 + lr;
          ga[i] = *(const bf16x8*)((char*)Gt + (lloc * 128 + (kb ^ SWZ64(lloc))));
        }
#pragma unroll
        for (int j = 0; j < 2; ++j) {
          const int p = wc + j * 16 + lr;
          xb[j] = *(const bf16x8*)((char*)Xt + (p * 128 + (kb ^ SWZ64(p))));
        }
#pragma unroll
        for (int i = 0; i < 2; ++i)
#pragma unroll
          for (int j = 0; j < 2; ++j)
            acc[i][j] = __builtin_amdgcn_mfma_f32_16x16x32_bf16(ga[i], xb[j], acc[i][j], 0, 0, 0);
      }
    }
    // epilogue: + D*x, write bf16 y
#pragma unroll
    for (int i = 0; i < 2; ++i)
#pragma unroll
      for (int j = 0; j < 2; ++j)
#pragma unroll
        for (int q = 0; q < 4; ++q) {
          const int lloc = wr + i * 16 + lk * 4 + q;
          const int grow = rowbase + l0 + lloc;
          const int p = wc + j * 16 + lr;
          const float xv = xconv[(size_t)grow * CONVD + h * HD + p];
          ybf[(size_t)grow * DSSM + h * HD + p] = f2bf(acc[i][j][q] + Dh * xv);
        }
  }
}

// ============================================================
// yg = y*silu(z); rmsnorm; output bf16 (feeds out-GEMM directly)
// ============================================================
__global__ __launch_bounds__(256) void gate_norm_kernel(
    const float* __restrict__ zx, const float* __restrict__ norm_w,
    const ushort* __restrict__ ybf, ushort* __restrict__ ygbf) {
  const int m = blockIdx.x;
  const int t = threadIdx.x;
  __shared__ float red[4];
  float g[8];
  float ssum = 0.f;
#pragma unroll
  for (int j = 0; j < 2; ++j) {
    const int cb = t * 4 + j * 1024;
    ushort4 yv = *(const ushort4*)&ybf[(size_t)m * DSSM + cb];
    float4 zv = *(const float4*)&zx[(size_t)m * DPROJ + cb];
    const float yy[4] = {bf2f(yv.x), bf2f(yv.y), bf2f(yv.z), bf2f(yv.w)};
    const float zz[4] = {zv.x, zv.y, zv.z, zv.w};
#pragma unroll
    for (int q = 0; q < 4; ++q) {
      const float gv = yy[q] * silu_f(zz[q]);
      g[j * 4 + q] = gv;
      ssum = fmaf(gv, gv, ssum);
    }
  }
#pragma unroll
  for (int off = 32; off > 0; off >>= 1) ssum += __shfl_down(ssum, off, 64);
  if ((t & 63) == 0) red[t >> 6] = ssum;
  __syncthreads();
  const float tot = red[0] + red[1] + red[2] + red[3];
  const float sc = 1.0f / sqrtf(tot / (float)DSSM + 1e-5f);
#pragma unroll
  for (int j = 0; j < 2; ++j) {
    const int cb = t * 4 + j * 1024;
    float4 nw = *(const float4*)&norm_w[cb];
    ushort4 o;
    o.x = f2bf(g[j * 4 + 0] * sc * nw.x);
    o.y = f2bf(g[j * 4 + 1] * sc * nw.y);
    o.z = f2bf(g[j * 4 + 2] * sc * nw.z);
    o.w = f2bf(g[j * 4 + 3] * sc * nw.w);
    *(ushort4*)&ygbf[(size_t)m * DSSM + cb] = o;
  }
}

// ============================================================
extern "C" void kernel_launch(void* const* d_in, const int* in_sizes, int n_in,
                              void* d_out, int out_size, void* d_ws, size_t ws_size,
                              hipStream_t stream) {
  const float* u          = (const float*)d_in[0];
  const float* in_proj_w  = (const float*)d_in[1];
  const float* conv_w     = (const float*)d_in[2];
  const float* conv_b     = (const float*)d_in[3];
  const float* dt_bias    = (const float*)d_in[4];
  const float* A_log      = (const float*)d_in[5];
  const float* Dp         = (const float*)d_in[6];
  const float* norm_w     = (const float*)d_in[7];
  const float* out_proj_w = (const float*)d_in[8];
  float* out = (float*)d_out;

  float* ws = (float*)d_ws;
  float* zx      = ws;                                   // 4096*4384 f32
  float* xconv   = zx      + (size_t)MROWS * DPROJ;      // 4096*2304 f32
  float* dt_bhl  = xconv   + (size_t)MROWS * CONVD;
  float* dA_bhl  = dt_bhl  + (size_t)B_SZ * NH * LQ;
  float* dA_cs   = dA_bhl  + (size_t)B_SZ * NH * LQ;
  float* Tg      = dA_cs   + (size_t)B_SZ * NH * LQ;
  float* statesR = Tg      + (size_t)B_SZ * NH * NC;     // 4.19M f32 region
  float* ybufR   = statesR + (size_t)B_SZ * NC * NH * HD * DST;  // 8.39M f32 region
  // bf16 aliases (footprint identical to round 2, ~161.5 MB):
  ushort* states_bf = (ushort*)statesR;                  // [0, 8.4MB) of states region
  ushort* prev_bf   = states_bf + (size_t)B_SZ * NC * NH * HD * DST;  // [8.4, 16.8MB)
  ushort* u_bf  = (ushort*)ybufR;                        // dead after in-gemm
  ushort* w_bf  = u_bf + (size_t)MROWS * DMODEL;         // dead after in-gemm
  ushort* y_bf  = (ushort*)ybufR;                        // y_kernel output (bf16)
  ushort* yg_bf = y_bf + (size_t)MROWS * DSSM;           // gate_norm output (bf16)
  ushort* ow_bf = (ushort*)xconv;                        // xconv dead after y_kernel

  const int n_u = MROWS * DMODEL;
  const int n_w = DPROJ * DMODEL;
  const int n_o = DMODEL * DSSM;

  // 1) casts for in_proj
  cast_f32_bf16_kernel<<<dim3(n_u / 1024), 256, 0, stream>>>(u, u_bf, n_u);
  cast_f32_bf16_kernel<<<dim3(n_w / 1024), 256, 0, stream>>>(in_proj_w, w_bf, n_w);
  // 2) zxbcdt = u @ in_proj_w^T
  gemm_nt_bf16<<<dim3((DPROJ + 127) / 128, MROWS / 128), 256, 0, stream>>>(
      u_bf, w_bf, zx, MROWS, DPROJ, DMODEL);
  // 3) fp32 dt / dA
  dt_kernel<<<dim3(MROWS), 256, 0, stream>>>(u, in_proj_w, dt_bias, A_log, dt_bhl, dA_bhl);
  // 4) causal dwconv + SiLU
  conv_kernel<<<dim3(B_SZ * (LQ / 16)), 256, 0, stream>>>(zx, conv_w, conv_b, xconv);
  // 5) per-chunk cumsum + intra-chunk states (MFMA, bf16 out)
  chunk_states_mfma<<<dim3(B_SZ * NC * NH), 256, 0, stream>>>(
      xconv, dt_bhl, dA_bhl, dA_cs, Tg, states_bf);
  // 6) inter-chunk recurrence (bf16 in/out, fp32 carry)
  chunk_scan_kernel<<<dim3(B_SZ * NH * 8), 256, 0, stream>>>(states_bf, prev_bf, Tg);
  // 7) Y = diag + off + D*x (MFMA, bf16 out)
  y_mfma_kernel<<<dim3(B_SZ * NC * NH), 256, 0, stream>>>(
      xconv, dt_bhl, dA_cs, prev_bf, Dp, y_bf);
  // 8) cast out_proj_w (xconv now dead)
  cast_f32_bf16_kernel<<<dim3(n_o / 1024), 256, 0, stream>>>(out_proj_w, ow_bf, n_o);
  // 9) gate + RMSNorm -> bf16
  gate_norm_kernel<<<dim3(MROWS), 256, 0, stream>>>(zx, norm_w, y_bf, yg_bf);
  // 10) out = yg @ out_proj_w^T
  gemm_nt_bf16<<<dim3(DMODEL / 128, MROWS / 128), 256, 0, stream>>>(
      yg_bf, ow_bf, out, MROWS, DMODEL, DSSM);
}

// Round 7
// 482.040 us; speedup vs baseline: 2.6342x; 1.1005x over previous
//
#include <hip/hip_runtime.h>
#include <cstdint>
#include <cstddef>

// ---------------- Mamba2 fwd: bf16-MFMA everywhere, bf16 activations ----------------
// B=2 L=2048 Dmodel=1024 Dssm=2048 H=32 P=64 N=128 chunk=256
#define B_SZ   2
#define LQ     2048
#define DMODEL 1024
#define DSSM   2048
#define NH     32
#define HD     64
#define DST    128
#define CONVD  2304
#define DPROJ  4384
#define NC     8
#define CHK    256
#define MROWS  (B_SZ*LQ)   // 4096

#define SWZ256(r) (((r) & 15) << 4)
#define SWZ64(r)  (((((r) & 7) ^ (((r) >> 3) & 7))) << 4)

__device__ __forceinline__ float silu_f(float x) { return x / (1.f + expf(-x)); }
__device__ __forceinline__ float softplus_f(float x) {
  return fmaxf(x, 0.f) + log1pf(expf(-fabsf(x)));
}
__device__ __forceinline__ ushort f2bf(float f) {  // RNE fp32->bf16
  uint32_t u = __float_as_uint(f);
  uint32_t r = (u + 0x7FFFu + ((u >> 16) & 1u)) >> 16;
  return (ushort)r;
}
__device__ __forceinline__ float bf2f(ushort u) {
  return __uint_as_float(((uint32_t)u) << 16);
}

typedef __bf16 bf16x8 __attribute__((ext_vector_type(8)));
typedef float f32x4 __attribute__((ext_vector_type(4)));

// ============================================================
// cast fp32 -> bf16 (as ushort), 4 elems/thread
// ============================================================
__global__ __launch_bounds__(256) void cast_f32_bf16_kernel(
    const float* __restrict__ in, ushort* __restrict__ out, int n) {
  const int i = (blockIdx.x * 256 + threadIdx.x) * 4;
  if (i >= n) return;
  float4 v = *(const float4*)&in[i];
  ushort4 o;
  o.x = f2bf(v.x); o.y = f2bf(v.y); o.z = f2bf(v.z); o.w = f2bf(v.w);
  *(ushort4*)&out[i] = o;
}

// ============================================================
// bf16 MFMA GEMM (NT): C[m][n] = sum_k A[m][k]*B[n][k].
// Operand-SWAPPED mfma so D's (lane>>4)*4+q axis = n -> vector stores.
// XCD-aware bijective block swizzle (requires nwg % 8 == 0).
// BF16OUT: ushort4 stores (bf16 C); else float4 stores (fp32 C).
// ============================================================
template<bool BF16OUT>
__global__ __launch_bounds__(256, 4) void gemm_nt_bf16(
    const ushort* __restrict__ A, const ushort* __restrict__ Bm,
    void* __restrict__ Cout, int M, int N, int K) {
  __shared__ ushort As[128 * 64];
  __shared__ ushort Bs[128 * 64];
  const int t = threadIdx.x;
  const int lane = t & 63;
  const int wid = t >> 6;
  const int wm = (wid >> 1) * 64;
  const int wn = (wid & 1) * 64;
  const int lr = lane & 15;
  const int lkb = (lane >> 4) * 8;   // k-elem offset for frag loads
  const int lk4 = (lane >> 4) * 4;   // n sub-offset in D
  // XCD swizzle: consecutive logical m-rows land on one XCD's L2
  const int gx = gridDim.x;
  int lin = blockIdx.y * gx + blockIdx.x;
  const int q8 = (gx * gridDim.y) >> 3;
  lin = (lin & 7) * q8 + (lin >> 3);
  const int m0 = (lin / gx) * 128;
  const int n0 = (lin % gx) * 128;
  const int srow = t >> 3;
  const int sce = (t & 7) * 8;

  f32x4 acc[4][4];
#pragma unroll
  for (int i = 0; i < 4; ++i)
#pragma unroll
    for (int j = 0; j < 4; ++j) acc[i][j] = (f32x4){0.f, 0.f, 0.f, 0.f};

  const int NT = K >> 6;
  for (int kt = 0; kt < NT; ++kt) {
    const int k0 = kt << 6;
    uint4 ar[4], br[4];
#pragma unroll
    for (int s2 = 0; s2 < 4; ++s2) {
      const int row = srow + s2 * 32;
      ar[s2] = *(const uint4*)&A[(size_t)(m0 + row) * K + k0 + sce];
      const int gn = n0 + row;
      br[s2] = (gn < N) ? *(const uint4*)&Bm[(size_t)gn * K + k0 + sce]
                        : make_uint4(0u, 0u, 0u, 0u);
    }
    __syncthreads();
#pragma unroll
    for (int s2 = 0; s2 < 4; ++s2) {
      const int row = srow + s2 * 32;
      const int e = (row * 64 + sce) ^ ((row & 7) << 3);
      *(uint4*)&As[e] = ar[s2];
      *(uint4*)&Bs[e] = br[s2];
    }
    __syncthreads();
#pragma unroll
    for (int ks = 0; ks < 2; ++ks) {
      bf16x8 af[4], bfr[4];
#pragma unroll
      for (int i = 0; i < 4; ++i) {
        const int ra = wm + i * 16 + lr;
        const int ea = (ra * 64 + ks * 32 + lkb) ^ ((ra & 7) << 3);
        af[i] = *(const bf16x8*)&As[ea];
        const int rb = wn + i * 16 + lr;
        const int eb = (rb * 64 + ks * 32 + lkb) ^ ((rb & 7) << 3);
        bfr[i] = *(const bf16x8*)&Bs[eb];
      }
      // swapped operands: D rows <- n (bfr), D cols <- m (af)
#pragma unroll
      for (int i = 0; i < 4; ++i)
#pragma unroll
        for (int j = 0; j < 4; ++j)
          acc[i][j] = __builtin_amdgcn_mfma_f32_16x16x32_bf16(bfr[j], af[i], acc[i][j], 0, 0, 0);
    }
  }
  // epilogue: lane holds C[m = m0+wm+i*16+lr][n = n0+wn+j*16+lk4 + q], q=0..3
#pragma unroll
  for (int i = 0; i < 4; ++i) {
    const int gm = m0 + wm + i * 16 + lr;
#pragma unroll
    for (int j = 0; j < 4; ++j) {
      const int gn = n0 + wn + j * 16 + lk4;
      if (gn < N) {
        if constexpr (BF16OUT) {
          ushort4 o;
          o.x = f2bf(acc[i][j][0]); o.y = f2bf(acc[i][j][1]);
          o.z = f2bf(acc[i][j][2]); o.w = f2bf(acc[i][j][3]);
          *(ushort4*)&((ushort*)Cout)[(size_t)gm * N + gn] = o;
        } else {
          *(float4*)&((float*)Cout)[(size_t)gm * N + gn] =
              make_float4(acc[i][j][0], acc[i][j][1], acc[i][j][2], acc[i][j][3]);
        }
      }
    }
  }
}

// ============================================================
// fp32 dt: recompute dt columns exactly (exp-amplified path)
// ============================================================
__global__ __launch_bounds__(256) void dt_kernel(
    const float* __restrict__ u, const float* __restrict__ w,
    const float* __restrict__ dt_bias, const float* __restrict__ A_log,
    float* __restrict__ dt_bhl, float* __restrict__ dA_bhl) {
  const int m = blockIdx.x;
  const int b = m >> 11;
  const int l = m & 2047;
  __shared__ float us[DMODEL];
  const int t = threadIdx.x;
  *(float4*)&us[t * 4] = *(const float4*)&u[(size_t)m * DMODEL + t * 4];
  __syncthreads();
  const int h = t >> 3;
  const int seg = t & 7;
  const float* wr = &w[(size_t)(DSSM + CONVD + h) * DMODEL + seg * 128];
  const float* uu = &us[seg * 128];
  float s = 0.f;
#pragma unroll
  for (int k = 0; k < 128; k += 4) {
    float4 wv = *(const float4*)&wr[k];
    s = fmaf(wv.x, uu[k + 0], s);
    s = fmaf(wv.y, uu[k + 1], s);
    s = fmaf(wv.z, uu[k + 2], s);
    s = fmaf(wv.w, uu[k + 3], s);
  }
  s += __shfl_down(s, 4, 8);
  s += __shfl_down(s, 2, 8);
  s += __shfl_down(s, 1, 8);
  if (seg == 0) {
    const float dtv = softplus_f(s + dt_bias[h]);
    const size_t o = ((size_t)b * NH + h) * LQ + l;
    dt_bhl[o] = dtv;
    dA_bhl[o] = -expf(A_log[h]) * dtv;
  }
}

// ============================================================
// Depthwise causal conv(K=4)+bias+SiLU over xBC. bf16 in/out, fp32 math.
// ============================================================
__global__ __launch_bounds__(256) void conv_kernel(
    const ushort* __restrict__ zx, const float* __restrict__ conv_w,
    const float* __restrict__ conv_b, ushort* __restrict__ xconv) {
  const int ROWS = 16;
  const int nrb = LQ / ROWS;
  const int blk = blockIdx.x;
  const int b = blk / nrb;
  const int r0 = (blk % nrb) * ROWS;
  const int t = threadIdx.x;

  float w0[9], w1[9], w2[9], w3[9], bsv[9], h0[9], h1[9], h2[9];
#pragma unroll
  for (int j = 0; j < 9; ++j) {
    const int cch = t + 256 * j;
    w0[j] = conv_w[cch * 4 + 0]; w1[j] = conv_w[cch * 4 + 1];
    w2[j] = conv_w[cch * 4 + 2]; w3[j] = conv_w[cch * 4 + 3];
    bsv[j] = conv_b[cch];
    h0[j] = (r0 - 3 >= 0) ? bf2f(zx[(size_t)(b * LQ + r0 - 3) * DPROJ + DSSM + cch]) : 0.f;
    h1[j] = (r0 - 2 >= 0) ? bf2f(zx[(size_t)(b * LQ + r0 - 2) * DPROJ + DSSM + cch]) : 0.f;
    h2[j] = (r0 - 1 >= 0) ? bf2f(zx[(size_t)(b * LQ + r0 - 1) * DPROJ + DSSM + cch]) : 0.f;
  }
  for (int r = 0; r < ROWS; ++r) {
    const size_t ibase = (size_t)(b * LQ + r0 + r) * DPROJ + DSSM;
    const size_t obase = (size_t)(b * LQ + r0 + r) * CONVD;
#pragma unroll
    for (int j = 0; j < 9; ++j) {
      const int cch = t + 256 * j;
      const float cur = bf2f(zx[ibase + cch]);
      float a = bsv[j] + w0[j] * h0[j] + w1[j] * h1[j] + w2[j] * h2[j] + w3[j] * cur;
      xconv[obase + cch] = f2bf(silu_f(a));
      h0[j] = h1[j]; h1[j] = h2[j]; h2[j] = cur;
    }
  }
}

// ============================================================
// Stage a [64 rows][128 cols] bf16 tile -> LDS, 256B pitch, SWZ256.
// 256 thr: 4/row, 32 ushorts (64B) each.
// ============================================================
__device__ __forceinline__ void stage_tile_128w(
    ushort* sh, const ushort* __restrict__ src, int src_stride, int t) {
  const int r = t >> 2;
  const int cb = (t & 3) * 32;
  const ushort* s = &src[(size_t)r * src_stride + cb];
  uint4 q0 = *(const uint4*)&s[0];
  uint4 q1 = *(const uint4*)&s[8];
  uint4 q2 = *(const uint4*)&s[16];
  uint4 q3 = *(const uint4*)&s[24];
  char* shb = (char*)sh + r * 256;
  const int c0 = cb * 2;
  *(uint4*)(shb + ((c0 +  0) ^ SWZ256(r))) = q0;
  *(uint4*)(shb + ((c0 + 16) ^ SWZ256(r))) = q1;
  *(uint4*)(shb + ((c0 + 32) ^ SWZ256(r))) = q2;
  *(uint4*)(shb + ((c0 + 48) ^ SWZ256(r))) = q3;
}

// ============================================================
// Per (b,c,h): cumsum(dA) scan + intra-chunk states via MFMA:
// states[p][n] = sum_l Xd[p][l] * Bd[n][l],  Xd = x*dt*exp(total-cs)
// ============================================================
__global__ __launch_bounds__(256) void chunk_states_mfma(
    const ushort* __restrict__ xconv, const float* __restrict__ dt_bhl,
    const float* __restrict__ dA_bhl, float* __restrict__ dA_cs_g,
    float* __restrict__ Tg, ushort* __restrict__ states_bf) {
  const int blk = blockIdx.x;
  const int h = blk & (NH - 1);
  const int c = (blk / NH) & (NC - 1);
  const int b = blk / (NH * NC);
  const int t = threadIdx.x;
  const int lane = t & 63;
  const int wid = t >> 6;
  const int lr = lane & 15;
  const int lk = lane >> 4;
  __shared__ float cs[CHK];
  __shared__ ushort Xt2[64 * 64];   // [p][l] 128B pitch, SWZ64
  __shared__ ushort Bt2[128 * 64];  // [n][l] 128B pitch, SWZ64
  const size_t bh = (size_t)b * NH + h;
  const int rowbase = b * LQ + c * CHK;

  cs[t] = dA_bhl[bh * LQ + c * CHK + t];
  __syncthreads();
#pragma unroll
  for (int off = 1; off < CHK; off <<= 1) {
    const float add = (t >= off) ? cs[t - off] : 0.f;
    __syncthreads();
    cs[t] += add;
    __syncthreads();
  }
  const float total = cs[CHK - 1];
  dA_cs_g[(bh * NC + c) * CHK + t] = cs[t];
  if (t == 0) Tg[bh * NC + c] = total;

  f32x4 acc[4][2];
#pragma unroll
  for (int i = 0; i < 4; ++i)
#pragma unroll
    for (int j = 0; j < 2; ++j) acc[i][j] = (f32x4){0.f, 0.f, 0.f, 0.f};

  for (int lt = 0; lt < 4; ++lt) {
    const int l0 = lt * 64;
    __syncthreads();
    {  // stage Xt2: rows l -> [p][l], factor dt*exp(total-cs)
      const int sr = t >> 2;
      const int pb = (t & 3) * 16;
      const float f = dt_bhl[bh * LQ + c * CHK + l0 + sr] * expf(total - cs[l0 + sr]);
      const ushort* xs = &xconv[(size_t)(rowbase + l0 + sr) * CONVD + h * HD + pb];
      ushort xv[16];
      *(uint4*)&xv[0] = *(const uint4*)&xs[0];
      *(uint4*)&xv[8] = *(const uint4*)&xs[8];
      char* Xb = (char*)Xt2;
#pragma unroll
      for (int e = 0; e < 16; ++e) {
        const int p = pb + e;
        *(ushort*)(Xb + (p * 128 + ((sr * 2) ^ SWZ64(p)))) = f2bf(bf2f(xv[e]) * f);
      }
    }
    {  // stage Bt2: rows l -> [n][l]
      const int sr = t >> 2;
      const int nb = (t & 3) * 32;
      const ushort* bs = &xconv[(size_t)(rowbase + l0 + sr) * CONVD + DSSM + nb];
      ushort bv[32];
      *(uint4*)&bv[0]  = *(const uint4*)&bs[0];
      *(uint4*)&bv[8]  = *(const uint4*)&bs[8];
      *(uint4*)&bv[16] = *(const uint4*)&bs[16];
      *(uint4*)&bv[24] = *(const uint4*)&bs[24];
      char* Bb = (char*)Bt2;
#pragma unroll
      for (int e = 0; e < 32; ++e) {
        const int n = nb + e;
        *(ushort*)(Bb + (n * 128 + ((sr * 2) ^ SWZ64(n)))) = bv[e];
      }
    }
    __syncthreads();
#pragma unroll
    for (int ks = 0; ks < 2; ++ks) {
      const int kb = (ks * 32 + lk * 8) * 2;
      bf16x8 a4[4], b2[2];
#pragma unroll
      for (int i = 0; i < 4; ++i) {
        const int p = i * 16 + lr;
        a4[i] = *(const bf16x8*)((char*)Xt2 + (p * 128 + (kb ^ SWZ64(p))));
      }
#pragma unroll
      for (int j = 0; j < 2; ++j) {
        const int n = wid * 32 + j * 16 + lr;
        b2[j] = *(const bf16x8*)((char*)Bt2 + (n * 128 + (kb ^ SWZ64(n))));
      }
#pragma unroll
      for (int i = 0; i < 4; ++i)
#pragma unroll
        for (int j = 0; j < 2; ++j)
          acc[i][j] = __builtin_amdgcn_mfma_f32_16x16x32_bf16(a4[i], b2[j], acc[i][j], 0, 0, 0);
    }
  }
  const size_t sbase = ((size_t)((b * NC + c) * NH) + h) * (HD * DST);
#pragma unroll
  for (int i = 0; i < 4; ++i)
#pragma unroll
    for (int j = 0; j < 2; ++j)
#pragma unroll
      for (int q = 0; q < 4; ++q) {
        const int p = i * 16 + lk * 4 + q;
        const int n = wid * 32 + j * 16 + lr;
        states_bf[sbase + (size_t)p * DST + n] = f2bf(acc[i][j][q]);
      }
}

// ============================================================
// Inter-chunk recurrence: reads states_bf, keeps P fp32, writes prev_bf.
// ============================================================
__global__ __launch_bounds__(256) void chunk_scan_kernel(
    const ushort* __restrict__ states_bf, ushort* __restrict__ prev_bf,
    const float* __restrict__ Tg) {
  const int blk = blockIdx.x;
  const int s = blk & 7;
  const int bh = blk >> 3;
  const int b = bh / NH;
  const int h = bh % NH;
  const int e = s * 1024 + threadIdx.x * 4;
  float4 P = make_float4(0.f, 0.f, 0.f, 0.f);
#pragma unroll
  for (int c = 0; c < NC; ++c) {
    const size_t idx = ((size_t)((b * NC + c) * NH) + h) * (HD * DST) + e;
    ushort4 s4 = *(const ushort4*)&states_bf[idx];
    ushort4 o;
    o.x = f2bf(P.x); o.y = f2bf(P.y); o.z = f2bf(P.z); o.w = f2bf(P.w);
    *(ushort4*)&prev_bf[idx] = o;
    const float ec = expf(Tg[(size_t)bh * NC + c]);
    P.x = fmaf(ec, P.x, bf2f(s4.x)); P.y = fmaf(ec, P.y, bf2f(s4.y));
    P.z = fmaf(ec, P.z, bf2f(s4.z)); P.w = fmaf(ec, P.w, bf2f(s4.w));
  }
}

// ============================================================
// Per (b,c,h): Y = (L ∘ C B^T) X + exp(cs)⊙(C prev^T) + D*x  via MFMA.
// ============================================================
__global__ __launch_bounds__(256) void y_mfma_kernel(
    const ushort* __restrict__ xconv, const float* __restrict__ dt_bhl,
    const float* __restrict__ dA_cs_g, const ushort* __restrict__ prevb,
    const float* __restrict__ Dp, ushort* __restrict__ ybf) {
  const int blk = blockIdx.x;
  const int h = blk & (NH - 1);
  const int c = (blk / NH) & (NC - 1);
  const int b = blk / (NH * NC);
  const int t = threadIdx.x;
  const int lane = t & 63;
  const int wid = t >> 6;
  const int wr = (wid >> 1) * 32;   // l-range base of this wave
  const int wc = (wid & 1) * 32;    // p/s-range base of this wave
  const int lr = lane & 15;
  const int lk = lane >> 4;
  __shared__ float cs[CHK];
  __shared__ ushort Ct[64 * 128];   // C tile, 256B pitch, SWZ256
  __shared__ ushort Bs[64 * 128];   // B tile, 256B pitch, SWZ256
  __shared__ ushort Gt[64 * 64];    // G tile (l x s), 128B pitch, SWZ64
  __shared__ ushort Xt[64 * 64];    // X^T tile (p x s), 128B pitch, SWZ64
  const size_t bh = (size_t)b * NH + h;
  const size_t prevbase = ((size_t)((b * NC + c) * NH) + h) * (HD * DST);
  const int rowbase = b * LQ + c * CHK;
  cs[t] = dA_cs_g[(bh * NC + c) * CHK + t];
  const float Dh = Dp[h];
  __syncthreads();

  for (int lt = 0; lt < 4; ++lt) {
    const int l0 = lt * 64;
    __syncthreads();  // protect Ct/Gt/Xt from previous iteration readers
    stage_tile_128w(Ct, &xconv[(size_t)(rowbase + l0) * CONVD + DSSM + DST], CONVD, t);
    __syncthreads();
    // cache A-fragments of C (reused by off-term and all G tiles)
    bf16x8 af[2][4];
#pragma unroll
    for (int i = 0; i < 2; ++i)
#pragma unroll
      for (int ks = 0; ks < 4; ++ks) {
        const int row = wr + i * 16 + lr;
        af[i][ks] = *(const bf16x8*)((char*)Ct +
            (row * 256 + (((ks * 32 + lk * 8) * 2) ^ SWZ256(row))));
      }
    // off-term: C @ prev^T (B-frags direct from global), then * exp(cs[l])
    f32x4 acc[2][2];
#pragma unroll
    for (int i = 0; i < 2; ++i)
#pragma unroll
      for (int j = 0; j < 2; ++j) acc[i][j] = (f32x4){0.f, 0.f, 0.f, 0.f};
#pragma unroll
    for (int ks = 0; ks < 4; ++ks) {
      bf16x8 bp[2];
#pragma unroll
      for (int j = 0; j < 2; ++j) {
        const int p = wc + j * 16 + lr;
        bp[j] = *(const bf16x8*)&prevb[prevbase + (size_t)p * DST + ks * 32 + lk * 8];
      }
#pragma unroll
      for (int i = 0; i < 2; ++i)
#pragma unroll
        for (int j = 0; j < 2; ++j)
          acc[i][j] = __builtin_amdgcn_mfma_f32_16x16x32_bf16(af[i][ks], bp[j], acc[i][j], 0, 0, 0);
    }
#pragma unroll
    for (int i = 0; i < 2; ++i) {
#pragma unroll
      for (int q = 0; q < 4; ++q) {
        const float e = expf(cs[l0 + wr + i * 16 + lk * 4 + q]);
        acc[i][0][q] *= e;
        acc[i][1][q] *= e;
      }
    }

    for (int st = 0; st <= lt; ++st) {
      const int s0 = st * 64;
      __syncthreads();  // prior Bs/Xt/Gt readers done
      stage_tile_128w(Bs, &xconv[(size_t)(rowbase + s0) * CONVD + DSSM], CONVD, t);
      {  // stage Xt: rows s of x*dt -> [p][s]
        const int sr = t >> 2;
        const int pb = (t & 3) * 16;
        const float f = dt_bhl[bh * LQ + c * CHK + s0 + sr];
        const ushort* xs = &xconv[(size_t)(rowbase + s0 + sr) * CONVD + h * HD + pb];
        ushort xv[16];
        *(uint4*)&xv[0] = *(const uint4*)&xs[0];
        *(uint4*)&xv[8] = *(const uint4*)&xs[8];
        char* Xb = (char*)Xt;
#pragma unroll
        for (int e = 0; e < 16; ++e) {
          const int p = pb + e;
          *(ushort*)(Xb + (p * 128 + ((sr * 2) ^ SWZ64(p)))) = f2bf(bf2f(xv[e]) * f);
        }
      }
      __syncthreads();
      // G = C B^T
      f32x4 g2[2][2];
#pragma unroll
      for (int i = 0; i < 2; ++i)
#pragma unroll
        for (int j = 0; j < 2; ++j) g2[i][j] = (f32x4){0.f, 0.f, 0.f, 0.f};
#pragma unroll
      for (int ks = 0; ks < 4; ++ks) {
        bf16x8 bb[2];
#pragma unroll
        for (int j = 0; j < 2; ++j) {
          const int srow = wc + j * 16 + lr;
          bb[j] = *(const bf16x8*)((char*)Bs +
              (srow * 256 + (((ks * 32 + lk * 8) * 2) ^ SWZ256(srow))));
        }
#pragma unroll
        for (int i = 0; i < 2; ++i)
#pragma unroll
          for (int j = 0; j < 2; ++j)
            g2[i][j] = __builtin_amdgcn_mfma_f32_16x16x32_bf16(af[i][ks], bb[j], g2[i][j], 0, 0, 0);
      }
      // decay + causal mask, write G (bf16) to LDS
      {
        char* Gb = (char*)Gt;
#pragma unroll
        for (int i = 0; i < 2; ++i) {
#pragma unroll
          for (int q = 0; q < 4; ++q) {
            const int lloc = wr + i * 16 + lk * 4 + q;
            const int labs = l0 + lloc;
            const float cl = cs[labs];
#pragma unroll
            for (int j = 0; j < 2; ++j) {
              const int sloc = wc + j * 16 + lr;
              const int sabs = s0 + sloc;
              const float gv = (labs >= sabs) ? g2[i][j][q] * expf(cl - cs[sabs]) : 0.f;
              *(ushort*)(Gb + (lloc * 128 + ((sloc * 2) ^ SWZ64(lloc)))) = f2bf(gv);
            }
          }
        }
      }
      __syncthreads();
      // Y += G X
#pragma unroll
      for (int ks2 = 0; ks2 < 2; ++ks2) {
        const int kb = (ks2 * 32 + lk * 8) * 2;
        bf16x8 ga[2], xb[2];
#pragma unroll
        for (int i = 0; i < 2; ++i) {
          const int lloc = wr + i * 16 + lr;
          ga[i] = *(const bf16x8*)((char*)Gt + (lloc * 128 + (kb ^ SWZ64(lloc))));
        }
#pragma unroll
        for (int j = 0; j < 2; ++j) {
          const int p = wc + j * 16 + lr;
          xb[j] = *(const bf16x8*)((char*)Xt + (p * 128 + (kb ^ SWZ64(p))));
        }
#pragma unroll
        for (int i = 0; i < 2; ++i)
#pragma unroll
          for (int j = 0; j < 2; ++j)
            acc[i][j] = __builtin_amdgcn_mfma_f32_16x16x32_bf16(ga[i], xb[j], acc[i][j], 0, 0, 0);
      }
    }
    // epilogue: + D*x, write bf16 y
#pragma unroll
    for (int i = 0; i < 2; ++i)
#pragma unroll
      for (int j = 0; j < 2; ++j)
#pragma unroll
        for (int q = 0; q < 4; ++q) {
          const int lloc = wr + i * 16 + lk * 4 + q;
          const int grow = rowbase + l0 + lloc;
          const int p = wc + j * 16 + lr;
          const float xv = bf2f(xconv[(size_t)grow * CONVD + h * HD + p]);
          ybf[(size_t)grow * DSSM + h * HD + p] = f2bf(acc[i][j][q] + Dh * xv);
        }
  }
}

// ============================================================
// yg = y*silu(z); rmsnorm; output bf16 (feeds out-GEMM directly)
// ============================================================
__global__ __launch_bounds__(256) void gate_norm_kernel(
    const ushort* __restrict__ zx, const float* __restrict__ norm_w,
    const ushort* __restrict__ ybf, ushort* __restrict__ ygbf) {
  const int m = blockIdx.x;
  const int t = threadIdx.x;
  __shared__ float red[4];
  float g[8];
  float ssum = 0.f;
#pragma unroll
  for (int j = 0; j < 2; ++j) {
    const int cb = t * 4 + j * 1024;
    ushort4 yv = *(const ushort4*)&ybf[(size_t)m * DSSM + cb];
    ushort4 zv = *(const ushort4*)&zx[(size_t)m * DPROJ + cb];
    const float yy[4] = {bf2f(yv.x), bf2f(yv.y), bf2f(yv.z), bf2f(yv.w)};
    const float zz[4] = {bf2f(zv.x), bf2f(zv.y), bf2f(zv.z), bf2f(zv.w)};
#pragma unroll
    for (int q = 0; q < 4; ++q) {
      const float gv = yy[q] * silu_f(zz[q]);
      g[j * 4 + q] = gv;
      ssum = fmaf(gv, gv, ssum);
    }
  }
#pragma unroll
  for (int off = 32; off > 0; off >>= 1) ssum += __shfl_down(ssum, off, 64);
  if ((t & 63) == 0) red[t >> 6] = ssum;
  __syncthreads();
  const float tot = red[0] + red[1] + red[2] + red[3];
  const float sc = 1.0f / sqrtf(tot / (float)DSSM + 1e-5f);
#pragma unroll
  for (int j = 0; j < 2; ++j) {
    const int cb = t * 4 + j * 1024;
    float4 nw = *(const float4*)&norm_w[cb];
    ushort4 o;
    o.x = f2bf(g[j * 4 + 0] * sc * nw.x);
    o.y = f2bf(g[j * 4 + 1] * sc * nw.y);
    o.z = f2bf(g[j * 4 + 2] * sc * nw.z);
    o.w = f2bf(g[j * 4 + 3] * sc * nw.w);
    *(ushort4*)&ygbf[(size_t)m * DSSM + cb] = o;
  }
}

// ============================================================
extern "C" void kernel_launch(void* const* d_in, const int* in_sizes, int n_in,
                              void* d_out, int out_size, void* d_ws, size_t ws_size,
                              hipStream_t stream) {
  const float* u          = (const float*)d_in[0];
  const float* in_proj_w  = (const float*)d_in[1];
  const float* conv_w     = (const float*)d_in[2];
  const float* conv_b     = (const float*)d_in[3];
  const float* dt_bias    = (const float*)d_in[4];
  const float* A_log      = (const float*)d_in[5];
  const float* Dp         = (const float*)d_in[6];
  const float* norm_w     = (const float*)d_in[7];
  const float* out_proj_w = (const float*)d_in[8];
  float* out = (float*)d_out;

  float* ws = (float*)d_ws;
  float* zxR     = ws;                                   // region (was 4096*4384 f32)
  float* xconvR  = zxR     + (size_t)MROWS * DPROJ;      // region (was 4096*2304 f32)
  float* dt_bhl  = xconvR  + (size_t)MROWS * CONVD;
  float* dA_bhl  = dt_bhl  + (size_t)B_SZ * NH * LQ;
  float* dA_cs   = dA_bhl  + (size_t)B_SZ * NH * LQ;
  float* Tg      = dA_cs   + (size_t)B_SZ * NH * LQ;
  float* statesR = Tg      + (size_t)B_SZ * NH * NC;     // 4.19M f32 region
  float* ybufR   = statesR + (size_t)B_SZ * NC * NH * HD * DST;  // 8.39M f32 region

  // bf16 views (same regions, footprint unchanged):
  ushort* zx_bf    = (ushort*)zxR;                       // 4096 x 4384 bf16
  ushort* xconv_bf = (ushort*)xconvR;                    // 4096 x 2304 bf16 (first half of region)
  ushort* ow_bf    = xconv_bf + (size_t)MROWS * CONVD;   // out_proj_w bf16, second half (disjoint)
  ushort* states_bf = (ushort*)statesR;                  // 8.4 MB
  ushort* prev_bf   = states_bf + (size_t)B_SZ * NC * NH * HD * DST;
  ushort* u_bf  = (ushort*)ybufR;                        // dead after in-gemm
  ushort* w_bf  = u_bf + (size_t)MROWS * DMODEL;         // dead after in-gemm
  ushort* y_bf  = (ushort*)ybufR;                        // y_mfma output (overwrites u_bf/w_bf)
  ushort* yg_bf = y_bf + (size_t)MROWS * DSSM;           // gate_norm output

  const int n_u = MROWS * DMODEL;
  const int n_w = DPROJ * DMODEL;
  const int n_o = DMODEL * DSSM;

  // 1) casts for in_proj
  cast_f32_bf16_kernel<<<dim3(n_u / 1024), 256, 0, stream>>>(u, u_bf, n_u);
  cast_f32_bf16_kernel<<<dim3(n_w / 1024), 256, 0, stream>>>(in_proj_w, w_bf, n_w);
  // 2) zxbcdt = u @ in_proj_w^T  (bf16 out, vector stores, XCD swizzle)
  gemm_nt_bf16<true><<<dim3((DPROJ + 127) / 128, MROWS / 128), 256, 0, stream>>>(
      u_bf, w_bf, zx_bf, MROWS, DPROJ, DMODEL);
  // 3) fp32 dt / dA
  dt_kernel<<<dim3(MROWS), 256, 0, stream>>>(u, in_proj_w, dt_bias, A_log, dt_bhl, dA_bhl);
  // 4) causal dwconv + SiLU (bf16 in/out)
  conv_kernel<<<dim3(B_SZ * (LQ / 16)), 256, 0, stream>>>(zx_bf, conv_w, conv_b, xconv_bf);
  // 5) per-chunk cumsum + intra-chunk states (MFMA, bf16 out)
  chunk_states_mfma<<<dim3(B_SZ * NC * NH), 256, 0, stream>>>(
      xconv_bf, dt_bhl, dA_bhl, dA_cs, Tg, states_bf);
  // 6) inter-chunk recurrence (bf16 in/out, fp32 carry)
  chunk_scan_kernel<<<dim3(B_SZ * NH * 8), 256, 0, stream>>>(states_bf, prev_bf, Tg);
  // 7) Y = diag + off + D*x (MFMA, bf16 out)
  y_mfma_kernel<<<dim3(B_SZ * NC * NH), 256, 0, stream>>>(
      xconv_bf, dt_bhl, dA_cs, prev_bf, Dp, y_bf);
  // 8) cast out_proj_w (into spare half of xconv region)
  cast_f32_bf16_kernel<<<dim3(n_o / 1024), 256, 0, stream>>>(out_proj_w, ow_bf, n_o);
  // 9) gate + RMSNorm -> bf16
  gate_norm_kernel<<<dim3(MROWS), 256, 0, stream>>>(zx_bf, norm_w, y_bf, yg_bf);
  // 10) out = yg @ out_proj_w^T (fp32 out, vector stores, XCD swizzle)
  gemm_nt_bf16<false><<<dim3(DMODEL / 128, MROWS / 128), 256, 0, stream>>>(
      yg_bf, ow_bf, out, MROWS, DMODEL, DSSM);
}